// Round 6
// baseline (234.433 us; speedup 1.0000x reference)
//
#include <hip/hip_runtime.h>
#include <math.h>

// MGNO layer: B=2, N=4096, C=64, ORDER=4, COORD=2, K=8
#define NNODES 4096
#define KNN 8
// 2-D grid: 64x64 cells over [-4.5, 4.5]^2; edge cells absorb clamped points.
#define GX 64
#define NCELL (GX * GX)
#define BOX_LO (-4.5f)
#define CELL_INV (7.11111111f)   // GX / 9.0

__device__ __forceinline__ int binf(float v) {
    int k = (int)floorf((v - BOX_LO) * CELL_INV);
    return min(GX - 1, max(0, k));
}

__device__ __forceinline__ float cleanf(float v) {
    if (v != v) return 0.0f;
    return fminf(fmaxf(v, -1.0e6f), 1.0e6f);
}

__device__ __forceinline__ float gelu_tanh(float v) {
    float v3 = v * v * v;
    float t = tanhf(0.7978845608028654f * (v + 0.044715f * v3));
    return 0.5f * v * (1.0f + t);
}

__device__ __forceinline__ float wave_sum64(float v) {
    #pragma unroll
    for (int off = 32; off > 0; off >>= 1)
        v += __shfl_xor(v, off, 64);
    return v;
}

// ---------------------------------------------------------------------------
// Kernel 0: prep. Blocks 0-1: clean pos, counting-sort into 64x64 cells
// (one block/batch). Blocks 2-7: transpose ALL weight matrices into ws for
// per-lane-column b128 LDS layouts (runs on otherwise-idle CUs).
// ---------------------------------------------------------------------------
__global__ __launch_bounds__(1024) void prep_kernel(
    const float* __restrict__ pos, float4* __restrict__ spk,
    int* __restrict__ boff,
    const float* __restrict__ mw,  const float* __restrict__ mW1,
    const float* __restrict__ mW2, const float* __restrict__ uW1,
    const float* __restrict__ uW2,
    float* __restrict__ mWlt, float* __restrict__ mW1tA,
    float* __restrict__ mW1tB, float* __restrict__ uW1t,
    float* __restrict__ uW2t, float* __restrict__ mW2t)
{
    __shared__ int cnt[NCELL];       // 16 KB; reused as scatter cursor
    __shared__ int wsum[16], wexcl[16];

    if (blockIdx.x >= 2) {
        // ---- weight transposes (idle CUs; prep proper is 2 blocks) ----
        int tid = (blockIdx.x - 2) * 1024 + threadIdx.x;  // 0..6143
        const int STEP = 6 * 1024;
        // mWlt[o][j][i] = W[i][j][o]  (W flat: (i*64+j)*5+o)
        for (int g = tid; g < 5 * 64 * 64; g += STEP) {
            int o = g >> 12, rem = g & 4095, j = rem >> 6, i = rem & 63;
            mWlt[g] = mw[(i * 64 + j) * 5 + o];
        }
        // mW1tA[j][i] = mW1[i][j]; mW1tB[j][i] = mW1[64+i][j]  (128x64 halves)
        for (int g = tid; g < 64 * 64; g += STEP) {
            int j = g >> 6, i = g & 63;
            mW1tA[g] = mW1[i * 64 + j];
            mW1tB[g] = mW1[(64 + i) * 64 + j];
        }
        // uW1t[j][i] = uW1[i][j]   (128x128)
        for (int g = tid; g < 128 * 128; g += STEP) {
            int j = g >> 7, i = g & 127;
            uW1t[g] = uW1[i * 128 + j];
        }
        // uW2t[j][h] = uW2[h][j]   (uW2 is 128x64 -> 64x128)
        for (int g = tid; g < 64 * 128; g += STEP) {
            int j = g >> 7, h = g & 127;
            uW2t[g] = uW2[h * 64 + j];
        }
        // mW2t[j][h] = mW2[h][j]   (64x64)
        for (int g = tid; g < 64 * 64; g += STEP) {
            int j = g >> 6, h = g & 63;
            mW2t[g] = mW2[h * 64 + j];
        }
        return;
    }

    int b    = blockIdx.x;
    int t    = threadIdx.x;
    int wid  = t >> 6;
    int lane = t & 63;
    const float2* pb = (const float2*)(pos + (size_t)b * NNODES * 2);

    float qx[4], qy[4];
    int ck[4];
    #pragma unroll
    for (int s = 0; s < 4; ++s) cnt[t + s * 1024] = 0;
    __syncthreads();

    #pragma unroll
    for (int s = 0; s < 4; ++s) {
        float2 p = pb[t + s * 1024];
        qx[s] = cleanf(p.x); qy[s] = cleanf(p.y);
        ck[s] = binf(qy[s]) * GX + binf(qx[s]);
        atomicAdd(&cnt[ck[s]], 1);
    }
    __syncthreads();

    // exclusive prefix scan of cnt[4096]: 4 cells/thread + wave/block scan
    int c0 = cnt[4 * t], c1 = cnt[4 * t + 1], c2 = cnt[4 * t + 2], c3 = cnt[4 * t + 3];
    int s4 = c0 + c1 + c2 + c3;
    int sc = s4;
    #pragma unroll
    for (int off = 1; off < 64; off <<= 1) {
        int o = __shfl_up(sc, off, 64);
        if (lane >= off) sc += o;
    }
    if (lane == 63) wsum[wid] = sc;
    __syncthreads();
    if (t < 16) {
        int v = wsum[t];
        #pragma unroll
        for (int off = 1; off < 16; off <<= 1) {
            int o = __shfl_up(v, off, 64);
            if (t >= off) v += o;
        }
        wexcl[t] = v - wsum[t];
    }
    __syncthreads();
    int base = wexcl[wid] + (sc - s4);
    int* bofb = boff + b * (NCELL + 1);
    bofb[4 * t]     = base;
    bofb[4 * t + 1] = base + c0;
    bofb[4 * t + 2] = base + c0 + c1;
    bofb[4 * t + 3] = base + c0 + c1 + c2;
    if (t == 0) bofb[NCELL] = NNODES;
    cnt[4 * t]     = base;
    cnt[4 * t + 1] = base + c0;
    cnt[4 * t + 2] = base + c0 + c1;
    cnt[4 * t + 3] = base + c0 + c1 + c2;
    __syncthreads();

    #pragma unroll
    for (int s = 0; s < 4; ++s) {
        int p = atomicAdd(&cnt[ck[s]], 1);
        spk[(size_t)b * NNODES + p] =
            make_float4(qx[s], qy[s], __int_as_float(t + s * 1024), 0.0f);
    }
}

#define INSERT8(cur)                                                     \
    {                                                                    \
        unsigned long long c_ = (cur);                                   \
        _Pragma("unroll")                                                \
        for (int q_ = 0; q_ < 8; ++q_) {                                 \
            unsigned long long mn_ = (c_ < best[q_]) ? c_ : best[q_];    \
            c_ = (c_ < best[q_]) ? best[q_] : c_;                        \
            best[q_] = mn_;                                              \
        }                                                                \
    }

// ---------------------------------------------------------------------------
// Kernel 1: exact 8-NN via 2-D cell grid, one wave per query row. (R2 verbatim)
// ---------------------------------------------------------------------------
__global__ __launch_bounds__(512) void knn_kernel(
    const float* __restrict__ pos, const float4* __restrict__ spk,
    const int* __restrict__ boff, int* __restrict__ nbr)
{
    int wid  = threadIdx.x >> 6;
    int lane = threadIdx.x & 63;
    int row  = blockIdx.x * 8 + wid;          // 0..8191
    int b    = row >> 12;
    int i    = row & 4095;

    const float4* sp = spk + (size_t)b * NNODES;
    const int*    bo = boff + b * (NCELL + 1);

    float2 pr = ((const float2*)(pos + (size_t)b * NNODES * 2))[i];
    float qx = cleanf(pr.x), qy = cleanf(pr.y);
    int qcx = binf(qx), qcy = binf(qy);

    unsigned long long best[8];
    #pragma unroll
    for (int q = 0; q < 8; ++q) best[q] = ~0ull;

    auto sweep = [&](int s0, int s1) {
        for (int p0 = s0; p0 < s1; p0 += 64) {
            int p = p0 + lane;
            bool valid = (p < s1);
            float4 cp = sp[min(p, s1 - 1)];
            int ci = __float_as_int(cp.z);
            float dx = qx - cp.x, dy = qy - cp.y;
            float d2 = __fadd_rn(__fmul_rn(dx, dx), __fmul_rn(dy, dy));
            unsigned long long cur =
                ((unsigned long long)__float_as_uint(d2) << 32) | (unsigned)ci;
            if (!valid || ci == i) cur = ~0ull;
            INSERT8(cur);
        }
    };

    // ---- phase A: widen square (counts only) until >= 9 points ----
    int r = 1, cxL, cxH, cyL, cyH;
    for (;;) {
        cxL = max(qcx - r, 0); cxH = min(qcx + r, GX - 1);
        cyL = max(qcy - r, 0); cyH = min(qcy + r, GX - 1);
        int cnt = 0;
        for (int cy = cyL; cy <= cyH; ++cy)
            cnt += bo[cy * GX + cxH + 1] - bo[cy * GX + cxL];
        if (cnt >= 9 || (cxL == 0 && cxH == GX - 1 && cyL == 0 && cyH == GX - 1))
            break;
        r += (r < 4) ? 1 : (r >> 1);         // geometric growth in tails
    }
    for (int cy = cyL; cy <= cyH; ++cy)
        sweep(bo[cy * GX + cxL], bo[cy * GX + cxH + 1]);

    // ---- extract exact top-8 of phase A (ascending) into m8[] ----
    unsigned long long m8[8];
    #pragma unroll
    for (int rr = 0; rr < 8; ++rr) {
        unsigned long long k = best[0];
        #pragma unroll
        for (int off = 32; off > 0; off >>= 1) {
            unsigned long long o = __shfl_xor(k, off, 64);
            k = (o < k) ? o : k;
        }
        m8[rr] = k;
        if (best[0] == k) {
            #pragma unroll
            for (int q = 0; q < 7; ++q) best[q] = best[q + 1];
            best[7] = ~0ull;
        }
    }

    // window half-width from U = 8th-smallest d2 (finite by construction)
    float U = __uint_as_float((unsigned)(m8[7] >> 32));
    float w = sqrtf(U) * 1.0001f + 1.0e-5f;
    int bxlo = binf(qx - w), bxhi = binf(qx + w);
    int bylo = binf(qy - w), byhi = binf(qy + w);

    // reinit per-lane lists; inject m8[r] into lane r (static-index select)
    #pragma unroll
    for (int q = 0; q < 8; ++q) best[q] = ~0ull;
    unsigned long long inj = m8[0];
    #pragma unroll
    for (int rr = 1; rr < 8; ++rr) inj = (lane == rr) ? m8[rr] : inj;
    if (lane < 8) best[0] = inj;

    // ---- phase B: B-square minus A-square (exact exclusion, no dup keys) ----
    for (int cy = bylo; cy <= byhi; ++cy) {
        int rl = bo[cy * GX + bxlo], rh = bo[cy * GX + bxhi + 1];
        if (cy >= cyL && cy <= cyH) {
            int e = bo[cy * GX + min(cxL, bxhi + 1)];   // left of A-cols
            sweep(rl, e);
            int s = bo[cy * GX + max(cxH + 1, bxlo)];   // right of A-cols
            sweep(s, rh);
        } else {
            sweep(rl, rh);
        }
    }

    // ---- final merge: 8 rounds of butterfly wave-min + pop ----
    unsigned out_j = 0;
    #pragma unroll
    for (int rr = 0; rr < 8; ++rr) {
        unsigned long long k = best[0];
        #pragma unroll
        for (int off = 32; off > 0; off >>= 1) {
            unsigned long long o = __shfl_xor(k, off, 64);
            k = (o < k) ? o : k;
        }
        if (lane == rr) out_j = (unsigned)k;
        if (best[0] == k) {                  // unique keys -> exactly one lane
            #pragma unroll
            for (int q = 0; q < 7; ++q) best[q] = best[q + 1];
            best[7] = ~0ull;
        }
    }
    if (lane < 8) nbr[(size_t)row * KNN + lane] = (int)out_j;
}

// ---------------------------------------------------------------------------
// Kernel 2: fused multipole + msg GEMM. (R5 verbatim — validated: b128-column
// weights pad-68, float4 same-address activation broadcasts, 0 conflicts.)
// ---------------------------------------------------------------------------
__global__ __launch_bounds__(512) void multipole_gemm_kernel(
    const float* __restrict__ x, const float* __restrict__ pos,
    const float* __restrict__ mWlt, const float* __restrict__ mW1tA,
    const float* __restrict__ mW1tB, const float* __restrict__ osc,
    const float* __restrict__ lns, const float* __restrict__ lnb,
    float* __restrict__ mp, float* __restrict__ ab)
{
    __shared__ alignas(16) float Wl[5 * 64 * 68];   // [o][j][i] pad-68, 85 KB
    __shared__ alignas(16) float WA[64 * 68];       // 17 KB
    __shared__ alignas(16) float WB[64 * 68];       // 17 KB
    __shared__ alignas(16) float xsh[32][68];       // cleaned x, 8.5 KB
    __shared__ alignas(16) float xr[32][68];        // raw x, 8.5 KB
    __shared__ float csh[32][5];                    // per-node c_o
    int base = blockIdx.x * 32;

    // stage transposed weights: coalesced global float4, conflict-free LDS
    for (int g = threadIdx.x; g < 5 * 64 * 16; g += 512) {
        int oj = g >> 4, i4 = (g & 15) * 4;
        *(float4*)&Wl[oj * 68 + i4] = *(const float4*)&mWlt[oj * 64 + i4];
    }
    for (int g = threadIdx.x; g < 64 * 16; g += 512) {
        int j = g >> 4, i4 = (g & 15) * 4;
        *(float4*)&WA[j * 68 + i4] = *(const float4*)&mW1tA[j * 64 + i4];
        *(float4*)&WB[j * 68 + i4] = *(const float4*)&mW1tB[j * 64 + i4];
    }
    for (int g = threadIdx.x; g < 32 * 64; g += 512) {
        float v = x[(size_t)base * 64 + g];
        xr[g >> 6][g & 63]  = v;
        xsh[g >> 6][g & 63] = cleanf(v);
    }
    __syncthreads();

    if (threadIdx.x < 32) {
        int t = threadIdx.x;
        float ss = 0.0f;
        for (int i = 0; i < 64; ++i) { float v = xsh[t][i]; ss += v * v; }
        float nx = sqrtf(ss);
        int node = base + t;
        float px = cleanf(pos[(size_t)node * 2]);
        float py = cleanf(pos[(size_t)node * 2 + 1]);
        float r = fmaxf(sqrtf(px * px + py * py), 1.0e-8f);
        float th = atan2f(py, px + 1.0e-8f);
        float r2 = r * r, r3 = r2 * r, r4 = r2 * r2;  // lax.integer_pow order
        float ro[5] = {1.0f, r, r2, r3, r4};
        #pragma unroll
        for (int o = 0; o < 5; ++o) {
            float radial = tanhf(ro[o] / (1.0f + ro[o]));
            float ang = cosf((float)o * th);
            float s = radial * ang;
            float denom = fabsf(s) * nx + 1.0e-8f;     // ||s*x|| + EPS
            float sc = fminf(fmaxf(osc[o], 0.01f), 1.0f);
            csh[t][o] = (s / denom) * sc / (float)(o + 1);
        }
    }
    __syncthreads();

    int w = threadIdx.x >> 6;
    int lane = threadIdx.x & 63;
    int nl0 = w * 4;

    float acc[4][5];
    float accA[4] = {0.f, 0.f, 0.f, 0.f};
    float accB[4] = {0.f, 0.f, 0.f, 0.f};
    #pragma unroll
    for (int r_ = 0; r_ < 4; ++r_)
        #pragma unroll
        for (int o = 0; o < 5; ++o) acc[r_][o] = 0.0f;

    #define MG_FMA(R, XI, XV, QC)                                          \
        { float xi_ = (XI), xv_ = (XV);                                    \
          acc[R][0] += xi_ * q0.QC; acc[R][1] += xi_ * q1.QC;              \
          acc[R][2] += xi_ * q2.QC; acc[R][3] += xi_ * q3.QC;              \
          acc[R][4] += xi_ * q4.QC;                                        \
          accA[R] += xv_ * qa.QC;  accB[R] += xv_ * qb.QC; }

    for (int i4 = 0; i4 < 64; i4 += 4) {   // 7 w-b128 + 8 act-b128-bc / iter
        float4 q0 = *(const float4*)&Wl[(0 * 64 + lane) * 68 + i4];
        float4 q1 = *(const float4*)&Wl[(1 * 64 + lane) * 68 + i4];
        float4 q2 = *(const float4*)&Wl[(2 * 64 + lane) * 68 + i4];
        float4 q3 = *(const float4*)&Wl[(3 * 64 + lane) * 68 + i4];
        float4 q4 = *(const float4*)&Wl[(4 * 64 + lane) * 68 + i4];
        float4 qa = *(const float4*)&WA[lane * 68 + i4];
        float4 qb = *(const float4*)&WB[lane * 68 + i4];
        #pragma unroll
        for (int r_ = 0; r_ < 4; ++r_) {
            float4 xc4 = *(const float4*)&xsh[nl0 + r_][i4];  // broadcast
            float4 xw4 = *(const float4*)&xr[nl0 + r_][i4];   // broadcast
            MG_FMA(r_, xc4.x, xw4.x, x)
            MG_FMA(r_, xc4.y, xw4.y, y)
            MG_FMA(r_, xc4.z, xw4.z, z)
            MG_FMA(r_, xc4.w, xw4.w, w)
        }
    }
    #undef MG_FMA

    float lnsv = lns[lane], lnbv = lnb[lane];
    #pragma unroll
    for (int r_ = 0; r_ < 4; ++r_) {
        int node = base + nl0 + r_;
        float tv = csh[nl0 + r_][0] * acc[r_][0] + csh[nl0 + r_][1] * acc[r_][1]
                 + csh[nl0 + r_][2] * acc[r_][2] + csh[nl0 + r_][3] * acc[r_][3]
                 + csh[nl0 + r_][4] * acc[r_][4];
        float mu = wave_sum64(tv) * (1.0f / 64.0f);
        float dv = tv - mu;
        float var = wave_sum64(dv * dv) * (1.0f / 64.0f);
        float o_ = dv * (1.0f / sqrtf(var + 1.0e-6f)) * lnsv + lnbv;
        if (o_ != o_) o_ = xsh[nl0 + r_][lane];  // where(isnan, cleaned x)
        mp[(size_t)node * 64 + lane] = o_;
        ab[(size_t)node * 128 + lane]      = accA[r_];
        ab[(size_t)node * 128 + 64 + lane] = accB[r_];
    }
}

// ---------------------------------------------------------------------------
// Kernel 3: fused msg-gather + update MLP + final LayerNorm.
// ISOLATION TEST vs R4: batched-b128 matvec structure ONLY — original node
// order, no p2s/spk/swizzle. Per wave: 4 nodes; gather+gelu sequential with
// rolling prefetch (R2 pattern); then the three matvecs batched so each
// b128 weight read feeds 4 nodes (2112 b32 -> ~432 b128 LDS instrs/wave).
// ab/mp/x rows loaded at point of use (minimize live registers / spill risk).
// Accumulation sequences identical to R2 -> bit-identical outputs.
// LDS: 66K W1ut + 33K W2ut + 17K W2mt + 16.5K ul + 16.5K hl = 149 KB.
// ---------------------------------------------------------------------------
__global__ __launch_bounds__(512) void msg_upd_kernel(
    const float* __restrict__ x, const float* __restrict__ ab,
    const int* __restrict__ nbr, const float* __restrict__ mp,
    const float* __restrict__ mb1, const float* __restrict__ mW2t,
    const float* __restrict__ mb2,
    const float* __restrict__ uW1t, const float* __restrict__ ub1,
    const float* __restrict__ uW2t, const float* __restrict__ ub2,
    const float* __restrict__ lns, const float* __restrict__ lnb,
    float* __restrict__ out)
{
    __shared__ alignas(16) float W1ul[128 * 132];  // [j][i] pad-132, 66 KB
    __shared__ alignas(16) float W2ul[64 * 132];   // [j][h] pad-132, 33 KB
    __shared__ alignas(16) float W2ml[64 * 68];    // [j][h] pad-68, 17 KB
    __shared__ alignas(16) float ul[8][4][132];    // u = [mp|lm], 16.5 KB
    __shared__ alignas(16) float hl[8][4][132];    // hm then hidden, 16.5 KB

    for (int g = threadIdx.x; g < 128 * 32; g += 512) {
        int j = g >> 5, i4 = (g & 31) * 4;
        *(float4*)&W1ul[j * 132 + i4] = *(const float4*)&uW1t[j * 128 + i4];
    }
    for (int g = threadIdx.x; g < 64 * 32; g += 512) {
        int j = g >> 5, h4 = (g & 31) * 4;
        *(float4*)&W2ul[j * 132 + h4] = *(const float4*)&uW2t[j * 128 + h4];
    }
    for (int g = threadIdx.x; g < 64 * 16; g += 512) {
        int j = g >> 4, h4 = (g & 15) * 4;
        *(float4*)&W2ml[j * 68 + h4] = *(const float4*)&mW2t[j * 64 + h4];
    }
    __syncthreads();

    int w = threadIdx.x >> 6;
    int lane = threadIdx.x & 63;
    float b1m = mb1[lane], b2m = mb2[lane];
    float b1a = ub1[lane], b1b = ub1[lane + 64], b2u = ub2[lane];
    float lnsv = lns[lane], lnbv = lnb[lane];

    int node0 = blockIdx.x * 32 + w * 4;                   // original order
    const float* abb = ab + (((size_t)(node0 >> 12)) << 12) * 128;  // batch base
    const int* nb = nbr + (size_t)node0 * 8;

    // ---- gather + gelu, per node sequential with rolling prefetch ----
    float bvc[8];
    #pragma unroll
    for (int k = 0; k < 8; ++k)
        bvc[k] = abb[(size_t)nb[k] * 128 + 64 + lane];
    #pragma unroll
    for (int r = 0; r < 4; ++r) {
        float a = ab[(size_t)(node0 + r) * 128 + lane];    // load at use
        float bvn[8];
        if (r < 3) {
            #pragma unroll
            for (int k = 0; k < 8; ++k)
                bvn[k] = abb[(size_t)nb[8 * (r + 1) + k] * 128 + 64 + lane];
        }
        float hsum = 0.0f;
        #pragma unroll
        for (int k = 0; k < 8; ++k)
            hsum += gelu_tanh(a + bvc[k] + b1m);
        hl[w][r][lane] = hsum * 0.125f;    // same-wave LDS, in-order
        if (r < 3) {
            #pragma unroll
            for (int k = 0; k < 8; ++k) bvc[k] = bvn[k];
        }
    }

    // ---- msg W2 batched: lm_r = hm_r @ W2m + b2 (h ascending) ----
    float o_[4] = {0.f, 0.f, 0.f, 0.f};
    #pragma unroll
    for (int h4 = 0; h4 < 64; h4 += 4) {
        float4 wq = *(const float4*)&W2ml[lane * 68 + h4];
        #pragma unroll
        for (int r = 0; r < 4; ++r) {
            float4 hv = *(const float4*)&hl[w][r][h4];     // broadcast
            o_[r] += hv.x * wq.x + hv.y * wq.y + hv.z * wq.z + hv.w * wq.w;
        }
    }

    // ---- u = [mp | lm] ----
    #pragma unroll
    for (int r = 0; r < 4; ++r) {
        ul[w][r][lane]      = mp[(size_t)(node0 + r) * 64 + lane];  // at use
        ul[w][r][64 + lane] = o_[r] + b2m;
    }

    // ---- upd W1 batched (i ascending 0..127) ----
    float h1a[4] = {0.f, 0.f, 0.f, 0.f}, h2a[4] = {0.f, 0.f, 0.f, 0.f};
    #pragma unroll
    for (int i4 = 0; i4 < 128; i4 += 4) {
        float4 w1 = *(const float4*)&W1ul[lane * 132 + i4];
        float4 w2 = *(const float4*)&W1ul[(lane + 64) * 132 + i4];
        #pragma unroll
        for (int r = 0; r < 4; ++r) {
            float4 uq = *(const float4*)&ul[w][r][i4];     // broadcast
            h1a[r] += uq.x * w1.x + uq.y * w1.y + uq.z * w1.z + uq.w * w1.w;
            h2a[r] += uq.x * w2.x + uq.y * w2.y + uq.z * w2.z + uq.w * w2.w;
        }
    }
    #pragma unroll
    for (int r = 0; r < 4; ++r) {
        hl[w][r][lane]      = gelu_tanh(h1a[r] + b1a);     // overwrites hm (dead)
        hl[w][r][64 + lane] = gelu_tanh(h2a[r] + b1b);
    }

    // ---- upd W2 batched (h ascending 0..127) ----
    float accq[4] = {0.f, 0.f, 0.f, 0.f};
    #pragma unroll
    for (int h4 = 0; h4 < 128; h4 += 4) {
        float4 wq = *(const float4*)&W2ul[lane * 132 + h4];
        #pragma unroll
        for (int r = 0; r < 4; ++r) {
            float4 hv = *(const float4*)&hl[w][r][h4];     // broadcast
            accq[r] += hv.x * wq.x + hv.y * wq.y + hv.z * wq.z + hv.w * wq.w;
        }
    }

    // ---- residual + LayerNorm (identical butterfly) ----
    #pragma unroll
    for (int r = 0; r < 4; ++r) {
        float pre = x[(size_t)(node0 + r) * 64 + lane] + accq[r] + b2u;
        float mu = wave_sum64(pre) * (1.0f / 64.0f);
        float dv = pre - mu;
        float var = wave_sum64(dv * dv) * (1.0f / 64.0f);
        out[(size_t)(node0 + r) * 64 + lane] =
            dv * (1.0f / sqrtf(var + 1.0e-6f)) * lnsv + lnbv;
    }
}

extern "C" void kernel_launch(void* const* d_in, const int* in_sizes, int n_in,
                              void* d_out, int out_size, void* d_ws, size_t ws_size,
                              hipStream_t stream)
{
    (void)in_sizes; (void)n_in; (void)out_size; (void)ws_size;
    const float* x     = (const float*)d_in[0];
    const float* pos   = (const float*)d_in[1];
    const float* mw    = (const float*)d_in[2];
    const float* osc   = (const float*)d_in[3];
    const float* mplns = (const float*)d_in[4];
    const float* mplnb = (const float*)d_in[5];
    const float* mW1   = (const float*)d_in[6];
    const float* mb1   = (const float*)d_in[7];
    const float* mW2   = (const float*)d_in[8];
    const float* mb2   = (const float*)d_in[9];
    const float* uW1   = (const float*)d_in[10];
    const float* ub1   = (const float*)d_in[11];
    const float* uW2   = (const float*)d_in[12];
    const float* ub2   = (const float*)d_in[13];
    const float* olns  = (const float*)d_in[14];
    const float* olnb  = (const float*)d_in[15];
    float* out = (float*)d_out;

    // ws layout (bytes):
    //   0        nbr    262144
    //   262144   mp     2097152
    //   2359296  ab     4194304
    //   6553600  spk    131072
    //   6684672  boff   36864 (2*4097*4 used)
    //   6721536  mWlt   81920
    //   6803456  mW1tA  16384
    //   6819840  mW1tB  16384
    //   6836224  uW1t   65536
    //   6901760  uW2t   32768
    //   6934528  mW2t   16384
    char* ws = (char*)d_ws;
    int*    nbr   = (int*)ws;
    float*  mp    = (float*)(ws + 262144);
    float*  ab    = (float*)(ws + 2359296);
    float4* spk   = (float4*)(ws + 6553600);
    int*    boff  = (int*)(ws + 6684672);
    float*  mWlt  = (float*)(ws + 6721536);
    float*  mW1tA = (float*)(ws + 6803456);
    float*  mW1tB = (float*)(ws + 6819840);
    float*  uW1t  = (float*)(ws + 6836224);
    float*  uW2t  = (float*)(ws + 6901760);
    float*  mW2t  = (float*)(ws + 6934528);

    prep_kernel<<<8, 1024, 0, stream>>>(pos, spk, boff,
        mw, mW1, mW2, uW1, uW2, mWlt, mW1tA, mW1tB, uW1t, uW2t, mW2t);
    knn_kernel<<<1024, 512, 0, stream>>>(pos, spk, boff, nbr);
    multipole_gemm_kernel<<<256, 512, 0, stream>>>(
        x, pos, mWlt, mW1tA, mW1tB, osc, mplns, mplnb, mp, ab);
    msg_upd_kernel<<<256, 512, 0, stream>>>(
        x, ab, nbr, mp, mb1, mW2t, mb2, uW1t, ub1, uW2t, ub2, olns, olnb, out);
}

// Round 7
// 114.034 us; speedup vs baseline: 2.0558x; 2.0558x over previous
//
#include <hip/hip_runtime.h>
#include <math.h>

// MGNO layer: B=2, N=4096, C=64, ORDER=4, COORD=2, K=8
#define NNODES 4096
#define KNN 8
// 2-D grid: 64x64 cells over [-4.5, 4.5]^2; edge cells absorb clamped points.
#define GX 64
#define NCELL (GX * GX)
#define BOX_LO (-4.5f)
#define CELL_INV (7.11111111f)   // GX / 9.0

__device__ __forceinline__ int binf(float v) {
    int k = (int)floorf((v - BOX_LO) * CELL_INV);
    return min(GX - 1, max(0, k));
}

__device__ __forceinline__ float cleanf(float v) {
    if (v != v) return 0.0f;
    return fminf(fmaxf(v, -1.0e6f), 1.0e6f);
}

__device__ __forceinline__ float gelu_tanh(float v) {
    float v3 = v * v * v;
    float t = tanhf(0.7978845608028654f * (v + 0.044715f * v3));
    return 0.5f * v * (1.0f + t);
}

__device__ __forceinline__ float wave_sum64(float v) {
    #pragma unroll
    for (int off = 32; off > 0; off >>= 1)
        v += __shfl_xor(v, off, 64);
    return v;
}

// ---------------------------------------------------------------------------
// Kernel 0: prep. Blocks 0-1: clean pos, counting-sort into 64x64 cells
// (one block/batch). Blocks 2-7: transpose ALL weight matrices into ws for
// per-lane-column b128 LDS layouts (runs on otherwise-idle CUs).
// ---------------------------------------------------------------------------
__global__ __launch_bounds__(1024) void prep_kernel(
    const float* __restrict__ pos, float4* __restrict__ spk,
    int* __restrict__ boff,
    const float* __restrict__ mw,  const float* __restrict__ mW1,
    const float* __restrict__ mW2, const float* __restrict__ uW1,
    const float* __restrict__ uW2,
    float* __restrict__ mWlt, float* __restrict__ mW1tA,
    float* __restrict__ mW1tB, float* __restrict__ uW1t,
    float* __restrict__ uW2t, float* __restrict__ mW2t)
{
    __shared__ int cnt[NCELL];       // 16 KB; reused as scatter cursor
    __shared__ int wsum[16], wexcl[16];

    if (blockIdx.x >= 2) {
        // ---- weight transposes (idle CUs; prep proper is 2 blocks) ----
        int tid = (blockIdx.x - 2) * 1024 + threadIdx.x;  // 0..6143
        const int STEP = 6 * 1024;
        // mWlt[o][j][i] = W[i][j][o]  (W flat: (i*64+j)*5+o)
        for (int g = tid; g < 5 * 64 * 64; g += STEP) {
            int o = g >> 12, rem = g & 4095, j = rem >> 6, i = rem & 63;
            mWlt[g] = mw[(i * 64 + j) * 5 + o];
        }
        // mW1tA[j][i] = mW1[i][j]; mW1tB[j][i] = mW1[64+i][j]  (128x64 halves)
        for (int g = tid; g < 64 * 64; g += STEP) {
            int j = g >> 6, i = g & 63;
            mW1tA[g] = mW1[i * 64 + j];
            mW1tB[g] = mW1[(64 + i) * 64 + j];
        }
        // uW1t[j][i] = uW1[i][j]   (128x128)
        for (int g = tid; g < 128 * 128; g += STEP) {
            int j = g >> 7, i = g & 127;
            uW1t[g] = uW1[i * 128 + j];
        }
        // uW2t[j][h] = uW2[h][j]   (uW2 is 128x64 -> 64x128)
        for (int g = tid; g < 64 * 128; g += STEP) {
            int j = g >> 7, h = g & 127;
            uW2t[g] = uW2[h * 64 + j];
        }
        // mW2t[j][h] = mW2[h][j]   (64x64)
        for (int g = tid; g < 64 * 64; g += STEP) {
            int j = g >> 6, h = g & 63;
            mW2t[g] = mW2[h * 64 + j];
        }
        return;
    }

    int b    = blockIdx.x;
    int t    = threadIdx.x;
    int wid  = t >> 6;
    int lane = t & 63;
    const float2* pb = (const float2*)(pos + (size_t)b * NNODES * 2);

    float qx[4], qy[4];
    int ck[4];
    #pragma unroll
    for (int s = 0; s < 4; ++s) cnt[t + s * 1024] = 0;
    __syncthreads();

    #pragma unroll
    for (int s = 0; s < 4; ++s) {
        float2 p = pb[t + s * 1024];
        qx[s] = cleanf(p.x); qy[s] = cleanf(p.y);
        ck[s] = binf(qy[s]) * GX + binf(qx[s]);
        atomicAdd(&cnt[ck[s]], 1);
    }
    __syncthreads();

    // exclusive prefix scan of cnt[4096]: 4 cells/thread + wave/block scan
    int c0 = cnt[4 * t], c1 = cnt[4 * t + 1], c2 = cnt[4 * t + 2], c3 = cnt[4 * t + 3];
    int s4 = c0 + c1 + c2 + c3;
    int sc = s4;
    #pragma unroll
    for (int off = 1; off < 64; off <<= 1) {
        int o = __shfl_up(sc, off, 64);
        if (lane >= off) sc += o;
    }
    if (lane == 63) wsum[wid] = sc;
    __syncthreads();
    if (t < 16) {
        int v = wsum[t];
        #pragma unroll
        for (int off = 1; off < 16; off <<= 1) {
            int o = __shfl_up(v, off, 64);
            if (t >= off) v += o;
        }
        wexcl[t] = v - wsum[t];
    }
    __syncthreads();
    int base = wexcl[wid] + (sc - s4);
    int* bofb = boff + b * (NCELL + 1);
    bofb[4 * t]     = base;
    bofb[4 * t + 1] = base + c0;
    bofb[4 * t + 2] = base + c0 + c1;
    bofb[4 * t + 3] = base + c0 + c1 + c2;
    if (t == 0) bofb[NCELL] = NNODES;
    cnt[4 * t]     = base;
    cnt[4 * t + 1] = base + c0;
    cnt[4 * t + 2] = base + c0 + c1;
    cnt[4 * t + 3] = base + c0 + c1 + c2;
    __syncthreads();

    #pragma unroll
    for (int s = 0; s < 4; ++s) {
        int p = atomicAdd(&cnt[ck[s]], 1);
        spk[(size_t)b * NNODES + p] =
            make_float4(qx[s], qy[s], __int_as_float(t + s * 1024), 0.0f);
    }
}

#define INSERT8(cur)                                                     \
    {                                                                    \
        unsigned long long c_ = (cur);                                   \
        _Pragma("unroll")                                                \
        for (int q_ = 0; q_ < 8; ++q_) {                                 \
            unsigned long long mn_ = (c_ < best[q_]) ? c_ : best[q_];    \
            c_ = (c_ < best[q_]) ? best[q_] : c_;                        \
            best[q_] = mn_;                                              \
        }                                                                \
    }

// ---------------------------------------------------------------------------
// Kernel 1: exact 8-NN via 2-D cell grid, one wave per query row. (R2 verbatim)
// ---------------------------------------------------------------------------
__global__ __launch_bounds__(512) void knn_kernel(
    const float* __restrict__ pos, const float4* __restrict__ spk,
    const int* __restrict__ boff, int* __restrict__ nbr)
{
    int wid  = threadIdx.x >> 6;
    int lane = threadIdx.x & 63;
    int row  = blockIdx.x * 8 + wid;          // 0..8191
    int b    = row >> 12;
    int i    = row & 4095;

    const float4* sp = spk + (size_t)b * NNODES;
    const int*    bo = boff + b * (NCELL + 1);

    float2 pr = ((const float2*)(pos + (size_t)b * NNODES * 2))[i];
    float qx = cleanf(pr.x), qy = cleanf(pr.y);
    int qcx = binf(qx), qcy = binf(qy);

    unsigned long long best[8];
    #pragma unroll
    for (int q = 0; q < 8; ++q) best[q] = ~0ull;

    auto sweep = [&](int s0, int s1) {
        for (int p0 = s0; p0 < s1; p0 += 64) {
            int p = p0 + lane;
            bool valid = (p < s1);
            float4 cp = sp[min(p, s1 - 1)];
            int ci = __float_as_int(cp.z);
            float dx = qx - cp.x, dy = qy - cp.y;
            float d2 = __fadd_rn(__fmul_rn(dx, dx), __fmul_rn(dy, dy));
            unsigned long long cur =
                ((unsigned long long)__float_as_uint(d2) << 32) | (unsigned)ci;
            if (!valid || ci == i) cur = ~0ull;
            INSERT8(cur);
        }
    };

    // ---- phase A: widen square (counts only) until >= 9 points ----
    int r = 1, cxL, cxH, cyL, cyH;
    for (;;) {
        cxL = max(qcx - r, 0); cxH = min(qcx + r, GX - 1);
        cyL = max(qcy - r, 0); cyH = min(qcy + r, GX - 1);
        int cnt = 0;
        for (int cy = cyL; cy <= cyH; ++cy)
            cnt += bo[cy * GX + cxH + 1] - bo[cy * GX + cxL];
        if (cnt >= 9 || (cxL == 0 && cxH == GX - 1 && cyL == 0 && cyH == GX - 1))
            break;
        r += (r < 4) ? 1 : (r >> 1);         // geometric growth in tails
    }
    for (int cy = cyL; cy <= cyH; ++cy)
        sweep(bo[cy * GX + cxL], bo[cy * GX + cxH + 1]);

    // ---- extract exact top-8 of phase A (ascending) into m8[] ----
    unsigned long long m8[8];
    #pragma unroll
    for (int rr = 0; rr < 8; ++rr) {
        unsigned long long k = best[0];
        #pragma unroll
        for (int off = 32; off > 0; off >>= 1) {
            unsigned long long o = __shfl_xor(k, off, 64);
            k = (o < k) ? o : k;
        }
        m8[rr] = k;
        if (best[0] == k) {
            #pragma unroll
            for (int q = 0; q < 7; ++q) best[q] = best[q + 1];
            best[7] = ~0ull;
        }
    }

    // window half-width from U = 8th-smallest d2 (finite by construction)
    float U = __uint_as_float((unsigned)(m8[7] >> 32));
    float w = sqrtf(U) * 1.0001f + 1.0e-5f;
    int bxlo = binf(qx - w), bxhi = binf(qx + w);
    int bylo = binf(qy - w), byhi = binf(qy + w);

    // reinit per-lane lists; inject m8[r] into lane r (static-index select)
    #pragma unroll
    for (int q = 0; q < 8; ++q) best[q] = ~0ull;
    unsigned long long inj = m8[0];
    #pragma unroll
    for (int rr = 1; rr < 8; ++rr) inj = (lane == rr) ? m8[rr] : inj;
    if (lane < 8) best[0] = inj;

    // ---- phase B: B-square minus A-square (exact exclusion, no dup keys) ----
    for (int cy = bylo; cy <= byhi; ++cy) {
        int rl = bo[cy * GX + bxlo], rh = bo[cy * GX + bxhi + 1];
        if (cy >= cyL && cy <= cyH) {
            int e = bo[cy * GX + min(cxL, bxhi + 1)];   // left of A-cols
            sweep(rl, e);
            int s = bo[cy * GX + max(cxH + 1, bxlo)];   // right of A-cols
            sweep(s, rh);
        } else {
            sweep(rl, rh);
        }
    }

    // ---- final merge: 8 rounds of butterfly wave-min + pop ----
    unsigned out_j = 0;
    #pragma unroll
    for (int rr = 0; rr < 8; ++rr) {
        unsigned long long k = best[0];
        #pragma unroll
        for (int off = 32; off > 0; off >>= 1) {
            unsigned long long o = __shfl_xor(k, off, 64);
            k = (o < k) ? o : k;
        }
        if (lane == rr) out_j = (unsigned)k;
        if (best[0] == k) {                  // unique keys -> exactly one lane
            #pragma unroll
            for (int q = 0; q < 7; ++q) best[q] = best[q + 1];
            best[7] = ~0ull;
        }
    }
    if (lane < 8) nbr[(size_t)row * KNN + lane] = (int)out_j;
}

// ---------------------------------------------------------------------------
// Kernel 2: fused multipole + msg GEMM. (R5 verbatim — validated: b128-column
// weights pad-68, float4 same-address activation broadcasts, 0 conflicts.)
// ---------------------------------------------------------------------------
__global__ __launch_bounds__(512) void multipole_gemm_kernel(
    const float* __restrict__ x, const float* __restrict__ pos,
    const float* __restrict__ mWlt, const float* __restrict__ mW1tA,
    const float* __restrict__ mW1tB, const float* __restrict__ osc,
    const float* __restrict__ lns, const float* __restrict__ lnb,
    float* __restrict__ mp, float* __restrict__ ab)
{
    __shared__ alignas(16) float Wl[5 * 64 * 68];   // [o][j][i] pad-68, 85 KB
    __shared__ alignas(16) float WA[64 * 68];       // 17 KB
    __shared__ alignas(16) float WB[64 * 68];       // 17 KB
    __shared__ alignas(16) float xsh[32][68];       // cleaned x, 8.5 KB
    __shared__ alignas(16) float xr[32][68];        // raw x, 8.5 KB
    __shared__ float csh[32][5];                    // per-node c_o
    int base = blockIdx.x * 32;

    // stage transposed weights: coalesced global float4, conflict-free LDS
    for (int g = threadIdx.x; g < 5 * 64 * 16; g += 512) {
        int oj = g >> 4, i4 = (g & 15) * 4;
        *(float4*)&Wl[oj * 68 + i4] = *(const float4*)&mWlt[oj * 64 + i4];
    }
    for (int g = threadIdx.x; g < 64 * 16; g += 512) {
        int j = g >> 4, i4 = (g & 15) * 4;
        *(float4*)&WA[j * 68 + i4] = *(const float4*)&mW1tA[j * 64 + i4];
        *(float4*)&WB[j * 68 + i4] = *(const float4*)&mW1tB[j * 64 + i4];
    }
    for (int g = threadIdx.x; g < 32 * 64; g += 512) {
        float v = x[(size_t)base * 64 + g];
        xr[g >> 6][g & 63]  = v;
        xsh[g >> 6][g & 63] = cleanf(v);
    }
    __syncthreads();

    if (threadIdx.x < 32) {
        int t = threadIdx.x;
        float ss = 0.0f;
        for (int i = 0; i < 64; ++i) { float v = xsh[t][i]; ss += v * v; }
        float nx = sqrtf(ss);
        int node = base + t;
        float px = cleanf(pos[(size_t)node * 2]);
        float py = cleanf(pos[(size_t)node * 2 + 1]);
        float r = fmaxf(sqrtf(px * px + py * py), 1.0e-8f);
        float th = atan2f(py, px + 1.0e-8f);
        float r2 = r * r, r3 = r2 * r, r4 = r2 * r2;  // lax.integer_pow order
        float ro[5] = {1.0f, r, r2, r3, r4};
        #pragma unroll
        for (int o = 0; o < 5; ++o) {
            float radial = tanhf(ro[o] / (1.0f + ro[o]));
            float ang = cosf((float)o * th);
            float s = radial * ang;
            float denom = fabsf(s) * nx + 1.0e-8f;     // ||s*x|| + EPS
            float sc = fminf(fmaxf(osc[o], 0.01f), 1.0f);
            csh[t][o] = (s / denom) * sc / (float)(o + 1);
        }
    }
    __syncthreads();

    int w = threadIdx.x >> 6;
    int lane = threadIdx.x & 63;
    int nl0 = w * 4;

    float acc[4][5];
    float accA[4] = {0.f, 0.f, 0.f, 0.f};
    float accB[4] = {0.f, 0.f, 0.f, 0.f};
    #pragma unroll
    for (int r_ = 0; r_ < 4; ++r_)
        #pragma unroll
        for (int o = 0; o < 5; ++o) acc[r_][o] = 0.0f;

    #define MG_FMA(R, XI, XV, QC)                                          \
        { float xi_ = (XI), xv_ = (XV);                                    \
          acc[R][0] += xi_ * q0.QC; acc[R][1] += xi_ * q1.QC;              \
          acc[R][2] += xi_ * q2.QC; acc[R][3] += xi_ * q3.QC;              \
          acc[R][4] += xi_ * q4.QC;                                        \
          accA[R] += xv_ * qa.QC;  accB[R] += xv_ * qb.QC; }

    for (int i4 = 0; i4 < 64; i4 += 4) {   // 7 w-b128 + 8 act-b128-bc / iter
        float4 q0 = *(const float4*)&Wl[(0 * 64 + lane) * 68 + i4];
        float4 q1 = *(const float4*)&Wl[(1 * 64 + lane) * 68 + i4];
        float4 q2 = *(const float4*)&Wl[(2 * 64 + lane) * 68 + i4];
        float4 q3 = *(const float4*)&Wl[(3 * 64 + lane) * 68 + i4];
        float4 q4 = *(const float4*)&Wl[(4 * 64 + lane) * 68 + i4];
        float4 qa = *(const float4*)&WA[lane * 68 + i4];
        float4 qb = *(const float4*)&WB[lane * 68 + i4];
        #pragma unroll
        for (int r_ = 0; r_ < 4; ++r_) {
            float4 xc4 = *(const float4*)&xsh[nl0 + r_][i4];  // broadcast
            float4 xw4 = *(const float4*)&xr[nl0 + r_][i4];   // broadcast
            MG_FMA(r_, xc4.x, xw4.x, x)
            MG_FMA(r_, xc4.y, xw4.y, y)
            MG_FMA(r_, xc4.z, xw4.z, z)
            MG_FMA(r_, xc4.w, xw4.w, w)
        }
    }
    #undef MG_FMA

    float lnsv = lns[lane], lnbv = lnb[lane];
    #pragma unroll
    for (int r_ = 0; r_ < 4; ++r_) {
        int node = base + nl0 + r_;
        float tv = csh[nl0 + r_][0] * acc[r_][0] + csh[nl0 + r_][1] * acc[r_][1]
                 + csh[nl0 + r_][2] * acc[r_][2] + csh[nl0 + r_][3] * acc[r_][3]
                 + csh[nl0 + r_][4] * acc[r_][4];
        float mu = wave_sum64(tv) * (1.0f / 64.0f);
        float dv = tv - mu;
        float var = wave_sum64(dv * dv) * (1.0f / 64.0f);
        float o_ = dv * (1.0f / sqrtf(var + 1.0e-6f)) * lnsv + lnbv;
        if (o_ != o_) o_ = xsh[nl0 + r_][lane];  // where(isnan, cleaned x)
        mp[(size_t)node * 64 + lane] = o_;
        ab[(size_t)node * 128 + lane]      = accA[r_];
        ab[(size_t)node * 128 + 64 + lane] = accB[r_];
    }
}

// ---------------------------------------------------------------------------
// Kernel 3: fused msg-gather + update MLP + final LayerNorm.
// R2 skeleton VERBATIM (per-node sequential, rolling gather prefetch, small
// hm[8][64]/ul[8][128]/hl[8][128] staging — proven 39 us, no pathology) with
// EXACTLY ONE change: weight reads are per-lane-column ds_read_b128 from
// pre-transposed pad-132/68 LDS (R3-proven layout, 0 conflicts) instead of
// scalar b32. Same weight values in the same accumulation order -> bit-exact.
// NO 4-wide batching, NO [8][4][132] arrays (R4/R6's convicted structure).
// LDS: 66K W1ul + 33K W2ul + 17K W2ml + 2K hm + 4K ul + 4K hl = 129 KB.
// ---------------------------------------------------------------------------
__global__ __launch_bounds__(512) void msg_upd_kernel(
    const float* __restrict__ x, const float* __restrict__ ab,
    const int* __restrict__ nbr, const float* __restrict__ mp,
    const float* __restrict__ mb1, const float* __restrict__ mW2t,
    const float* __restrict__ mb2,
    const float* __restrict__ uW1t, const float* __restrict__ ub1,
    const float* __restrict__ uW2t, const float* __restrict__ ub2,
    const float* __restrict__ lns, const float* __restrict__ lnb,
    float* __restrict__ out)
{
    __shared__ alignas(16) float W1ul[128 * 132];  // [j][i] pad-132, 66 KB
    __shared__ alignas(16) float W2ul[64 * 132];   // [j][h] pad-132, 33 KB
    __shared__ alignas(16) float W2ml[64 * 68];    // [j][h] pad-68, 17 KB
    __shared__ alignas(16) float hm[8][64];        // 2 KB  (msg hidden mean)
    __shared__ alignas(16) float ul[8][128];       // 4 KB  (upd input)
    __shared__ alignas(16) float hl[8][128];       // 4 KB  (upd hidden)
    int base = blockIdx.x * 32;

    for (int g = threadIdx.x; g < 128 * 32; g += 512) {
        int j = g >> 5, i4 = (g & 31) * 4;
        *(float4*)&W1ul[j * 132 + i4] = *(const float4*)&uW1t[j * 128 + i4];
    }
    for (int g = threadIdx.x; g < 64 * 32; g += 512) {
        int j = g >> 5, h4 = (g & 31) * 4;
        *(float4*)&W2ul[j * 132 + h4] = *(const float4*)&uW2t[j * 128 + h4];
    }
    for (int g = threadIdx.x; g < 64 * 16; g += 512) {
        int j = g >> 4, h4 = (g & 15) * 4;
        *(float4*)&W2ml[j * 68 + h4] = *(const float4*)&mW2t[j * 64 + h4];
    }
    __syncthreads();

    int w = threadIdx.x >> 6;
    int lane = threadIdx.x & 63;
    float b1m = mb1[lane], b2m = mb2[lane];
    float b1a = ub1[lane], b1b = ub1[lane + 64], b2u = ub2[lane];
    float lnsv = lns[lane], lnbv = lnb[lane];

    int node0 = base + w * 4;
    const float* abb = ab + (((size_t)(node0 >> 12)) << 12) * 128;  // batch base
    const int* nb = nbr + (size_t)node0 * 8;

    // prologue: node t=0 neighbor B-rows
    float bvc[8];
    {
        int nb0[8];
        #pragma unroll
        for (int k = 0; k < 8; ++k) nb0[k] = nb[k];
        #pragma unroll
        for (int k = 0; k < 8; ++k)
            bvc[k] = abb[(size_t)nb0[k] * 128 + 64 + lane];
    }

    #pragma unroll
    for (int t = 0; t < 4; ++t) {
        int node = node0 + t;
        // issue next node's neighbor indices early
        int nbn[8];
        if (t < 3) {
            #pragma unroll
            for (int k = 0; k < 8; ++k) nbn[k] = nb[8 * (t + 1) + k];
        }
        float a  = ab[(size_t)node * 128 + lane];
        float mpv = mp[(size_t)node * 64 + lane];
        float xv  = x[(size_t)node * 64 + lane];

        // msg hidden: mean_k gelu(a + b_k + b1)   (same k-order as before)
        float hsum = 0.0f;
        #pragma unroll
        for (int k = 0; k < 8; ++k)
            hsum += gelu_tanh(a + bvc[k] + b1m);
        hm[w][lane] = hsum * 0.125f;   // same-wave LDS, in-order, no barrier

        // issue next node's B-row gathers (latency hidden under MLP below)
        float bvn[8];
        if (t < 3) {
            #pragma unroll
            for (int k = 0; k < 8; ++k)
                bvn[k] = abb[(size_t)nbn[k] * 128 + 64 + lane];
        }

        // lm = hm @ W2 + b2   (same h4-order; b128 weight column reads)
        float o_ = 0.0f;
        for (int h4 = 0; h4 < 64; h4 += 4) {
            float4 hv = *(const float4*)&hm[w][h4];           // broadcast
            float4 wq = *(const float4*)&W2ml[lane * 68 + h4];
            o_ += hv.x * wq.x + hv.y * wq.y + hv.z * wq.z + hv.w * wq.w;
        }

        // u = [mp | lm]
        ul[w][lane]      = mpv;
        ul[w][64 + lane] = o_ + b2m;

        // update MLP (same i4-order; b128 weight column reads)
        float h1a = 0.0f, h2a = 0.0f;
        for (int i4 = 0; i4 < 128; i4 += 4) {
            float4 uv = *(const float4*)&ul[w][i4];           // broadcast
            float4 w1 = *(const float4*)&W1ul[lane * 132 + i4];
            float4 w2 = *(const float4*)&W1ul[(lane + 64) * 132 + i4];
            h1a += uv.x * w1.x + uv.y * w1.y + uv.z * w1.z + uv.w * w1.w;
            h2a += uv.x * w2.x + uv.y * w2.y + uv.z * w2.z + uv.w * w2.w;
        }
        hl[w][lane]      = gelu_tanh(h1a + b1a);
        hl[w][64 + lane] = gelu_tanh(h2a + b1b);

        float acc = 0.0f;
        for (int h4 = 0; h4 < 128; h4 += 4) {
            float4 hv = *(const float4*)&hl[w][h4];           // broadcast
            float4 wq = *(const float4*)&W2ul[lane * 132 + h4];
            acc += hv.x * wq.x + hv.y * wq.y + hv.z * wq.z + hv.w * wq.w;
        }
        float pre = xv + acc + b2u;
        float mu = wave_sum64(pre) * (1.0f / 64.0f);
        float dv = pre - mu;
        float var = wave_sum64(dv * dv) * (1.0f / 64.0f);
        out[(size_t)node * 64 + lane] =
            dv * (1.0f / sqrtf(var + 1.0e-6f)) * lnsv + lnbv;

        // rotate pipeline
        #pragma unroll
        for (int k = 0; k < 8; ++k) bvc[k] = bvn[k];
    }
}

extern "C" void kernel_launch(void* const* d_in, const int* in_sizes, int n_in,
                              void* d_out, int out_size, void* d_ws, size_t ws_size,
                              hipStream_t stream)
{
    (void)in_sizes; (void)n_in; (void)out_size; (void)ws_size;
    const float* x     = (const float*)d_in[0];
    const float* pos   = (const float*)d_in[1];
    const float* mw    = (const float*)d_in[2];
    const float* osc   = (const float*)d_in[3];
    const float* mplns = (const float*)d_in[4];
    const float* mplnb = (const float*)d_in[5];
    const float* mW1   = (const float*)d_in[6];
    const float* mb1   = (const float*)d_in[7];
    const float* mW2   = (const float*)d_in[8];
    const float* mb2   = (const float*)d_in[9];
    const float* uW1   = (const float*)d_in[10];
    const float* ub1   = (const float*)d_in[11];
    const float* uW2   = (const float*)d_in[12];
    const float* ub2   = (const float*)d_in[13];
    const float* olns  = (const float*)d_in[14];
    const float* olnb  = (const float*)d_in[15];
    float* out = (float*)d_out;

    // ws layout (bytes):
    //   0        nbr    262144
    //   262144   mp     2097152
    //   2359296  ab     4194304
    //   6553600  spk    131072
    //   6684672  boff   36864 (2*4097*4 used)
    //   6721536  mWlt   81920
    //   6803456  mW1tA  16384
    //   6819840  mW1tB  16384
    //   6836224  uW1t   65536
    //   6901760  uW2t   32768
    //   6934528  mW2t   16384
    char* ws = (char*)d_ws;
    int*    nbr   = (int*)ws;
    float*  mp    = (float*)(ws + 262144);
    float*  ab    = (float*)(ws + 2359296);
    float4* spk   = (float4*)(ws + 6553600);
    int*    boff  = (int*)(ws + 6684672);
    float*  mWlt  = (float*)(ws + 6721536);
    float*  mW1tA = (float*)(ws + 6803456);
    float*  mW1tB = (float*)(ws + 6819840);
    float*  uW1t  = (float*)(ws + 6836224);
    float*  uW2t  = (float*)(ws + 6901760);
    float*  mW2t  = (float*)(ws + 6934528);

    prep_kernel<<<8, 1024, 0, stream>>>(pos, spk, boff,
        mw, mW1, mW2, uW1, uW2, mWlt, mW1tA, mW1tB, uW1t, uW2t, mW2t);
    knn_kernel<<<1024, 512, 0, stream>>>(pos, spk, boff, nbr);
    multipole_gemm_kernel<<<256, 512, 0, stream>>>(
        x, pos, mWlt, mW1tA, mW1tB, osc, mplns, mplnb, mp, ab);
    msg_upd_kernel<<<256, 512, 0, stream>>>(
        x, ab, nbr, mp, mb1, mW2t, mb2, uW1t, ub1, uW2t, ub2, olns, olnb, out);
}

// Round 8
// 84.127 us; speedup vs baseline: 2.7867x; 1.3555x over previous
//
#include <hip/hip_runtime.h>
#include <math.h>

// MGNO layer: B=2, N=4096, C=64, ORDER=4, COORD=2, K=8
#define NNODES 4096
#define KNN 8
// 2-D grid: 64x64 cells over [-4.5, 4.5]^2; edge cells absorb clamped points.
#define GX 64
#define NCELL (GX * GX)
#define BOX_LO (-4.5f)
#define CELL_INV (7.11111111f)   // GX / 9.0

__device__ __forceinline__ int binf(float v) {
    int k = (int)floorf((v - BOX_LO) * CELL_INV);
    return min(GX - 1, max(0, k));
}

__device__ __forceinline__ float cleanf(float v) {
    if (v != v) return 0.0f;
    return fminf(fmaxf(v, -1.0e6f), 1.0e6f);
}

__device__ __forceinline__ float gelu_tanh(float v) {
    float v3 = v * v * v;
    float t = tanhf(0.7978845608028654f * (v + 0.044715f * v3));
    return 0.5f * v * (1.0f + t);
}

__device__ __forceinline__ float wave_sum64(float v) {
    #pragma unroll
    for (int off = 32; off > 0; off >>= 1)
        v += __shfl_xor(v, off, 64);
    return v;
}

// ---------------------------------------------------------------------------
// Kernel 0: prep. Blocks 0-1: clean pos, counting-sort into 64x64 cells
// (one block/batch). Blocks 2-7: transpose multipole weights into ws for the
// b128-column LDS layout in multipole_gemm. (msg_upd uses original layouts —
// R7 proved strided-b128 weight reads LOSE to coalesced b32 rows there.)
// ---------------------------------------------------------------------------
__global__ __launch_bounds__(1024) void prep_kernel(
    const float* __restrict__ pos, float4* __restrict__ spk,
    int* __restrict__ boff,
    const float* __restrict__ mw,  const float* __restrict__ mW1,
    float* __restrict__ mWlt, float* __restrict__ mW1tA,
    float* __restrict__ mW1tB)
{
    __shared__ int cnt[NCELL];       // 16 KB; reused as scatter cursor
    __shared__ int wsum[16], wexcl[16];

    if (blockIdx.x >= 2) {
        // ---- weight transposes (idle CUs; prep proper is 2 blocks) ----
        int tid = (blockIdx.x - 2) * 1024 + threadIdx.x;  // 0..6143
        const int STEP = 6 * 1024;
        // mWlt[o][j][i] = W[i][j][o]  (W flat: (i*64+j)*5+o)
        for (int g = tid; g < 5 * 64 * 64; g += STEP) {
            int o = g >> 12, rem = g & 4095, j = rem >> 6, i = rem & 63;
            mWlt[g] = mw[(i * 64 + j) * 5 + o];
        }
        // mW1tA[j][i] = mW1[i][j]; mW1tB[j][i] = mW1[64+i][j]  (128x64 halves)
        for (int g = tid; g < 64 * 64; g += STEP) {
            int j = g >> 6, i = g & 63;
            mW1tA[g] = mW1[i * 64 + j];
            mW1tB[g] = mW1[(64 + i) * 64 + j];
        }
        return;
    }

    int b    = blockIdx.x;
    int t    = threadIdx.x;
    int wid  = t >> 6;
    int lane = t & 63;
    const float2* pb = (const float2*)(pos + (size_t)b * NNODES * 2);

    float qx[4], qy[4];
    int ck[4];
    #pragma unroll
    for (int s = 0; s < 4; ++s) cnt[t + s * 1024] = 0;
    __syncthreads();

    #pragma unroll
    for (int s = 0; s < 4; ++s) {
        float2 p = pb[t + s * 1024];
        qx[s] = cleanf(p.x); qy[s] = cleanf(p.y);
        ck[s] = binf(qy[s]) * GX + binf(qx[s]);
        atomicAdd(&cnt[ck[s]], 1);
    }
    __syncthreads();

    // exclusive prefix scan of cnt[4096]: 4 cells/thread + wave/block scan
    int c0 = cnt[4 * t], c1 = cnt[4 * t + 1], c2 = cnt[4 * t + 2], c3 = cnt[4 * t + 3];
    int s4 = c0 + c1 + c2 + c3;
    int sc = s4;
    #pragma unroll
    for (int off = 1; off < 64; off <<= 1) {
        int o = __shfl_up(sc, off, 64);
        if (lane >= off) sc += o;
    }
    if (lane == 63) wsum[wid] = sc;
    __syncthreads();
    if (t < 16) {
        int v = wsum[t];
        #pragma unroll
        for (int off = 1; off < 16; off <<= 1) {
            int o = __shfl_up(v, off, 64);
            if (t >= off) v += o;
        }
        wexcl[t] = v - wsum[t];
    }
    __syncthreads();
    int base = wexcl[wid] + (sc - s4);
    int* bofb = boff + b * (NCELL + 1);
    bofb[4 * t]     = base;
    bofb[4 * t + 1] = base + c0;
    bofb[4 * t + 2] = base + c0 + c1;
    bofb[4 * t + 3] = base + c0 + c1 + c2;
    if (t == 0) bofb[NCELL] = NNODES;
    cnt[4 * t]     = base;
    cnt[4 * t + 1] = base + c0;
    cnt[4 * t + 2] = base + c0 + c1;
    cnt[4 * t + 3] = base + c0 + c1 + c2;
    __syncthreads();

    #pragma unroll
    for (int s = 0; s < 4; ++s) {
        int p = atomicAdd(&cnt[ck[s]], 1);
        spk[(size_t)b * NNODES + p] =
            make_float4(qx[s], qy[s], __int_as_float(t + s * 1024), 0.0f);
    }
}

#define INSERT8(cur)                                                     \
    {                                                                    \
        unsigned long long c_ = (cur);                                   \
        _Pragma("unroll")                                                \
        for (int q_ = 0; q_ < 8; ++q_) {                                 \
            unsigned long long mn_ = (c_ < best[q_]) ? c_ : best[q_];    \
            c_ = (c_ < best[q_]) ? best[q_] : c_;                        \
            best[q_] = mn_;                                              \
        }                                                                \
    }

// ---------------------------------------------------------------------------
// Kernel 1: exact 8-NN via 2-D cell grid, one wave per query row. (R2 verbatim)
// ---------------------------------------------------------------------------
__global__ __launch_bounds__(512) void knn_kernel(
    const float* __restrict__ pos, const float4* __restrict__ spk,
    const int* __restrict__ boff, int* __restrict__ nbr)
{
    int wid  = threadIdx.x >> 6;
    int lane = threadIdx.x & 63;
    int row  = blockIdx.x * 8 + wid;          // 0..8191
    int b    = row >> 12;
    int i    = row & 4095;

    const float4* sp = spk + (size_t)b * NNODES;
    const int*    bo = boff + b * (NCELL + 1);

    float2 pr = ((const float2*)(pos + (size_t)b * NNODES * 2))[i];
    float qx = cleanf(pr.x), qy = cleanf(pr.y);
    int qcx = binf(qx), qcy = binf(qy);

    unsigned long long best[8];
    #pragma unroll
    for (int q = 0; q < 8; ++q) best[q] = ~0ull;

    auto sweep = [&](int s0, int s1) {
        for (int p0 = s0; p0 < s1; p0 += 64) {
            int p = p0 + lane;
            bool valid = (p < s1);
            float4 cp = sp[min(p, s1 - 1)];
            int ci = __float_as_int(cp.z);
            float dx = qx - cp.x, dy = qy - cp.y;
            float d2 = __fadd_rn(__fmul_rn(dx, dx), __fmul_rn(dy, dy));
            unsigned long long cur =
                ((unsigned long long)__float_as_uint(d2) << 32) | (unsigned)ci;
            if (!valid || ci == i) cur = ~0ull;
            INSERT8(cur);
        }
    };

    // ---- phase A: widen square (counts only) until >= 9 points ----
    int r = 1, cxL, cxH, cyL, cyH;
    for (;;) {
        cxL = max(qcx - r, 0); cxH = min(qcx + r, GX - 1);
        cyL = max(qcy - r, 0); cyH = min(qcy + r, GX - 1);
        int cnt = 0;
        for (int cy = cyL; cy <= cyH; ++cy)
            cnt += bo[cy * GX + cxH + 1] - bo[cy * GX + cxL];
        if (cnt >= 9 || (cxL == 0 && cxH == GX - 1 && cyL == 0 && cyH == GX - 1))
            break;
        r += (r < 4) ? 1 : (r >> 1);         // geometric growth in tails
    }
    for (int cy = cyL; cy <= cyH; ++cy)
        sweep(bo[cy * GX + cxL], bo[cy * GX + cxH + 1]);

    // ---- extract exact top-8 of phase A (ascending) into m8[] ----
    unsigned long long m8[8];
    #pragma unroll
    for (int rr = 0; rr < 8; ++rr) {
        unsigned long long k = best[0];
        #pragma unroll
        for (int off = 32; off > 0; off >>= 1) {
            unsigned long long o = __shfl_xor(k, off, 64);
            k = (o < k) ? o : k;
        }
        m8[rr] = k;
        if (best[0] == k) {
            #pragma unroll
            for (int q = 0; q < 7; ++q) best[q] = best[q + 1];
            best[7] = ~0ull;
        }
    }

    // window half-width from U = 8th-smallest d2 (finite by construction)
    float U = __uint_as_float((unsigned)(m8[7] >> 32));
    float w = sqrtf(U) * 1.0001f + 1.0e-5f;
    int bxlo = binf(qx - w), bxhi = binf(qx + w);
    int bylo = binf(qy - w), byhi = binf(qy + w);

    // reinit per-lane lists; inject m8[r] into lane r (static-index select)
    #pragma unroll
    for (int q = 0; q < 8; ++q) best[q] = ~0ull;
    unsigned long long inj = m8[0];
    #pragma unroll
    for (int rr = 1; rr < 8; ++rr) inj = (lane == rr) ? m8[rr] : inj;
    if (lane < 8) best[0] = inj;

    // ---- phase B: B-square minus A-square (exact exclusion, no dup keys) ----
    for (int cy = bylo; cy <= byhi; ++cy) {
        int rl = bo[cy * GX + bxlo], rh = bo[cy * GX + bxhi + 1];
        if (cy >= cyL && cy <= cyH) {
            int e = bo[cy * GX + min(cxL, bxhi + 1)];   // left of A-cols
            sweep(rl, e);
            int s = bo[cy * GX + max(cxH + 1, bxlo)];   // right of A-cols
            sweep(s, rh);
        } else {
            sweep(rl, rh);
        }
    }

    // ---- final merge: 8 rounds of butterfly wave-min + pop ----
    unsigned out_j = 0;
    #pragma unroll
    for (int rr = 0; rr < 8; ++rr) {
        unsigned long long k = best[0];
        #pragma unroll
        for (int off = 32; off > 0; off >>= 1) {
            unsigned long long o = __shfl_xor(k, off, 64);
            k = (o < k) ? o : k;
        }
        if (lane == rr) out_j = (unsigned)k;
        if (best[0] == k) {                  // unique keys -> exactly one lane
            #pragma unroll
            for (int q = 0; q < 7; ++q) best[q] = best[q + 1];
            best[7] = ~0ull;
        }
    }
    if (lane < 8) nbr[(size_t)row * KNN + lane] = (int)out_j;
}

// ---------------------------------------------------------------------------
// Kernel 2: fused multipole + msg GEMM. (R5 verbatim — validated: b128-column
// weights pad-68, float4 same-address activation broadcasts, 0 conflicts.)
// ---------------------------------------------------------------------------
__global__ __launch_bounds__(512) void multipole_gemm_kernel(
    const float* __restrict__ x, const float* __restrict__ pos,
    const float* __restrict__ mWlt, const float* __restrict__ mW1tA,
    const float* __restrict__ mW1tB, const float* __restrict__ osc,
    const float* __restrict__ lns, const float* __restrict__ lnb,
    float* __restrict__ mp, float* __restrict__ ab)
{
    __shared__ alignas(16) float Wl[5 * 64 * 68];   // [o][j][i] pad-68, 85 KB
    __shared__ alignas(16) float WA[64 * 68];       // 17 KB
    __shared__ alignas(16) float WB[64 * 68];       // 17 KB
    __shared__ alignas(16) float xsh[32][68];       // cleaned x, 8.5 KB
    __shared__ alignas(16) float xr[32][68];        // raw x, 8.5 KB
    __shared__ float csh[32][5];                    // per-node c_o
    int base = blockIdx.x * 32;

    // stage transposed weights: coalesced global float4, conflict-free LDS
    for (int g = threadIdx.x; g < 5 * 64 * 16; g += 512) {
        int oj = g >> 4, i4 = (g & 15) * 4;
        *(float4*)&Wl[oj * 68 + i4] = *(const float4*)&mWlt[oj * 64 + i4];
    }
    for (int g = threadIdx.x; g < 64 * 16; g += 512) {
        int j = g >> 4, i4 = (g & 15) * 4;
        *(float4*)&WA[j * 68 + i4] = *(const float4*)&mW1tA[j * 64 + i4];
        *(float4*)&WB[j * 68 + i4] = *(const float4*)&mW1tB[j * 64 + i4];
    }
    for (int g = threadIdx.x; g < 32 * 64; g += 512) {
        float v = x[(size_t)base * 64 + g];
        xr[g >> 6][g & 63]  = v;
        xsh[g >> 6][g & 63] = cleanf(v);
    }
    __syncthreads();

    if (threadIdx.x < 32) {
        int t = threadIdx.x;
        float ss = 0.0f;
        for (int i = 0; i < 64; ++i) { float v = xsh[t][i]; ss += v * v; }
        float nx = sqrtf(ss);
        int node = base + t;
        float px = cleanf(pos[(size_t)node * 2]);
        float py = cleanf(pos[(size_t)node * 2 + 1]);
        float r = fmaxf(sqrtf(px * px + py * py), 1.0e-8f);
        float th = atan2f(py, px + 1.0e-8f);
        float r2 = r * r, r3 = r2 * r, r4 = r2 * r2;  // lax.integer_pow order
        float ro[5] = {1.0f, r, r2, r3, r4};
        #pragma unroll
        for (int o = 0; o < 5; ++o) {
            float radial = tanhf(ro[o] / (1.0f + ro[o]));
            float ang = cosf((float)o * th);
            float s = radial * ang;
            float denom = fabsf(s) * nx + 1.0e-8f;     // ||s*x|| + EPS
            float sc = fminf(fmaxf(osc[o], 0.01f), 1.0f);
            csh[t][o] = (s / denom) * sc / (float)(o + 1);
        }
    }
    __syncthreads();

    int w = threadIdx.x >> 6;
    int lane = threadIdx.x & 63;
    int nl0 = w * 4;

    float acc[4][5];
    float accA[4] = {0.f, 0.f, 0.f, 0.f};
    float accB[4] = {0.f, 0.f, 0.f, 0.f};
    #pragma unroll
    for (int r_ = 0; r_ < 4; ++r_)
        #pragma unroll
        for (int o = 0; o < 5; ++o) acc[r_][o] = 0.0f;

    #define MG_FMA(R, XI, XV, QC)                                          \
        { float xi_ = (XI), xv_ = (XV);                                    \
          acc[R][0] += xi_ * q0.QC; acc[R][1] += xi_ * q1.QC;              \
          acc[R][2] += xi_ * q2.QC; acc[R][3] += xi_ * q3.QC;              \
          acc[R][4] += xi_ * q4.QC;                                        \
          accA[R] += xv_ * qa.QC;  accB[R] += xv_ * qb.QC; }

    for (int i4 = 0; i4 < 64; i4 += 4) {   // 7 w-b128 + 8 act-b128-bc / iter
        float4 q0 = *(const float4*)&Wl[(0 * 64 + lane) * 68 + i4];
        float4 q1 = *(const float4*)&Wl[(1 * 64 + lane) * 68 + i4];
        float4 q2 = *(const float4*)&Wl[(2 * 64 + lane) * 68 + i4];
        float4 q3 = *(const float4*)&Wl[(3 * 64 + lane) * 68 + i4];
        float4 q4 = *(const float4*)&Wl[(4 * 64 + lane) * 68 + i4];
        float4 qa = *(const float4*)&WA[lane * 68 + i4];
        float4 qb = *(const float4*)&WB[lane * 68 + i4];
        #pragma unroll
        for (int r_ = 0; r_ < 4; ++r_) {
            float4 xc4 = *(const float4*)&xsh[nl0 + r_][i4];  // broadcast
            float4 xw4 = *(const float4*)&xr[nl0 + r_][i4];   // broadcast
            MG_FMA(r_, xc4.x, xw4.x, x)
            MG_FMA(r_, xc4.y, xw4.y, y)
            MG_FMA(r_, xc4.z, xw4.z, z)
            MG_FMA(r_, xc4.w, xw4.w, w)
        }
    }
    #undef MG_FMA

    float lnsv = lns[lane], lnbv = lnb[lane];
    #pragma unroll
    for (int r_ = 0; r_ < 4; ++r_) {
        int node = base + nl0 + r_;
        float tv = csh[nl0 + r_][0] * acc[r_][0] + csh[nl0 + r_][1] * acc[r_][1]
                 + csh[nl0 + r_][2] * acc[r_][2] + csh[nl0 + r_][3] * acc[r_][3]
                 + csh[nl0 + r_][4] * acc[r_][4];
        float mu = wave_sum64(tv) * (1.0f / 64.0f);
        float dv = tv - mu;
        float var = wave_sum64(dv * dv) * (1.0f / 64.0f);
        float o_ = dv * (1.0f / sqrtf(var + 1.0e-6f)) * lnsv + lnbv;
        if (o_ != o_) o_ = xsh[nl0 + r_][lane];  // where(isnan, cleaned x)
        mp[(size_t)node * 64 + lane] = o_;
        ab[(size_t)node * 128 + lane]      = accA[r_];
        ab[(size_t)node * 128 + 64 + lane] = accB[r_];
    }
}

// ---------------------------------------------------------------------------
// Kernel 3: fused msg-gather + update MLP + final LayerNorm.
// Batch-4 matvecs, DE-RISKED: (a) weight reads are R2's coalesced b32 rows
// (W[h][lane]) — R7 proved strided-b128 is ~2x slower than its model;
// (b) NO unroll pragma on 16/32-trip loops — R4/R6's full unroll caused the
// 2KB/thread scratch-spill storm (FETCH ~264MB); (c) activations staged in
// small LDS arrays read as same-address float4 broadcasts (R2 mechanism);
// (d) gather/gelu phase is R2's rolling per-node form. Weight LDS traffic
// amortized 4x: 448 -> 112 b32/node. Expression trees verbatim -> bit-exact.
// LDS: 16K W2l + 64K W1u + 32K W2u + 16K ul + 16K hl = 144 KB -> 1 block/CU.
// ---------------------------------------------------------------------------
__global__ __launch_bounds__(512) void msg_upd_kernel(
    const float* __restrict__ x, const float* __restrict__ ab,
    const int* __restrict__ nbr, const float* __restrict__ mp,
    const float* __restrict__ mb1, const float* __restrict__ mW2,
    const float* __restrict__ mb2,
    const float* __restrict__ uW1, const float* __restrict__ ub1,
    const float* __restrict__ uW2, const float* __restrict__ ub2,
    const float* __restrict__ lns, const float* __restrict__ lnb,
    float* __restrict__ out)
{
    __shared__ float W2l[64][64];                 // 16 KB (msg W2)
    __shared__ float W1u[128][128];               // 64 KB (upd W1)
    __shared__ float W2u[128][64];                // 32 KB (upd W2)
    __shared__ alignas(16) float ul[8][4][128];   // 16 KB (upd input, 4 nodes)
    __shared__ alignas(16) float hl[8][4][128];   // 16 KB (hm in [0:64], then h)
    int base = blockIdx.x * 32;

    for (int g = threadIdx.x; g < 64 * 64; g += 512)   ((float*)W2l)[g] = mW2[g];
    for (int g = threadIdx.x; g < 128 * 128; g += 512) ((float*)W1u)[g] = uW1[g];
    for (int g = threadIdx.x; g < 128 * 64; g += 512)  ((float*)W2u)[g] = uW2[g];
    __syncthreads();

    int w = threadIdx.x >> 6;
    int lane = threadIdx.x & 63;
    float b1m = mb1[lane], b2m = mb2[lane];
    float b1a = ub1[lane], b1b = ub1[lane + 64], b2u = ub2[lane];
    float lnsv = lns[lane], lnbv = lnb[lane];

    int node0 = base + w * 4;
    const float* abb = ab + (((size_t)(node0 >> 12)) << 12) * 128;  // batch base
    const int* nb = nbr + (size_t)node0 * 8;

    // ---- gather + gelu phase (R2 rolling form; hm -> hl[w][t][0:64]) ----
    float bvc[8];
    {
        int nb0[8];
        #pragma unroll
        for (int k = 0; k < 8; ++k) nb0[k] = nb[k];
        #pragma unroll
        for (int k = 0; k < 8; ++k)
            bvc[k] = abb[(size_t)nb0[k] * 128 + 64 + lane];
    }
    #pragma unroll
    for (int t = 0; t < 4; ++t) {
        int nbn[8];
        if (t < 3) {
            #pragma unroll
            for (int k = 0; k < 8; ++k) nbn[k] = nb[8 * (t + 1) + k];
        }
        float a = ab[(size_t)(node0 + t) * 128 + lane];
        float bvn[8];
        if (t < 3) {
            #pragma unroll
            for (int k = 0; k < 8; ++k)
                bvn[k] = abb[(size_t)nbn[k] * 128 + 64 + lane];
        }
        float hsum = 0.0f;
        #pragma unroll
        for (int k = 0; k < 8; ++k)
            hsum += gelu_tanh(a + bvc[k] + b1m);
        hl[w][t][lane] = hsum * 0.125f;   // same-wave LDS, in-order
        #pragma unroll
        for (int k = 0; k < 8; ++k) bvc[k] = bvn[k];
    }

    // ---- msg W2 batched: lm_r = hm_r @ W2m + b2 (h ascending, same tree) ----
    float o_[4] = {0.f, 0.f, 0.f, 0.f};
    for (int h4 = 0; h4 < 64; h4 += 4) {          // no unroll (spill guard)
        float w0 = W2l[h4][lane],     w1 = W2l[h4 + 1][lane],
              w2 = W2l[h4 + 2][lane], w3 = W2l[h4 + 3][lane];
        #pragma unroll
        for (int r = 0; r < 4; ++r) {
            float4 hv = *(const float4*)&hl[w][r][h4];       // broadcast
            o_[r] += hv.x * w0 + hv.y * w1 + hv.z * w2 + hv.w * w3;
        }
    }

    // ---- u = [mp | lm] ----
    #pragma unroll
    for (int r = 0; r < 4; ++r) {
        ul[w][r][lane]      = mp[(size_t)(node0 + r) * 64 + lane];
        ul[w][r][64 + lane] = o_[r] + b2m;
    }

    // ---- upd W1 batched (i ascending 0..127, same tree) ----
    float h1a[4] = {0.f, 0.f, 0.f, 0.f}, h2a[4] = {0.f, 0.f, 0.f, 0.f};
    for (int i4 = 0; i4 < 128; i4 += 4) {         // no unroll (spill guard)
        float a0 = W1u[i4][lane],          a1 = W1u[i4 + 1][lane],
              a2 = W1u[i4 + 2][lane],      a3 = W1u[i4 + 3][lane];
        float c0 = W1u[i4][lane + 64],     c1 = W1u[i4 + 1][lane + 64],
              c2 = W1u[i4 + 2][lane + 64], c3 = W1u[i4 + 3][lane + 64];
        #pragma unroll
        for (int r = 0; r < 4; ++r) {
            float4 uv = *(const float4*)&ul[w][r][i4];       // broadcast
            h1a[r] += uv.x * a0 + uv.y * a1 + uv.z * a2 + uv.w * a3;
            h2a[r] += uv.x * c0 + uv.y * c1 + uv.z * c2 + uv.w * c3;
        }
    }
    #pragma unroll
    for (int r = 0; r < 4; ++r) {
        hl[w][r][lane]      = gelu_tanh(h1a[r] + b1a);   // hm now dead
        hl[w][r][64 + lane] = gelu_tanh(h2a[r] + b1b);
    }

    // ---- upd W2 batched (h ascending 0..127, same tree) ----
    float accq[4] = {0.f, 0.f, 0.f, 0.f};
    for (int h4 = 0; h4 < 128; h4 += 4) {         // no unroll (spill guard)
        float w0 = W2u[h4][lane],     w1 = W2u[h4 + 1][lane],
              w2 = W2u[h4 + 2][lane], w3 = W2u[h4 + 3][lane];
        #pragma unroll
        for (int r = 0; r < 4; ++r) {
            float4 hv = *(const float4*)&hl[w][r][h4];       // broadcast
            accq[r] += hv.x * w0 + hv.y * w1 + hv.z * w2 + hv.w * w3;
        }
    }

    // ---- residual + LayerNorm (identical butterfly) ----
    #pragma unroll
    for (int r = 0; r < 4; ++r) {
        float pre = x[(size_t)(node0 + r) * 64 + lane] + accq[r] + b2u;
        float mu = wave_sum64(pre) * (1.0f / 64.0f);
        float dv = pre - mu;
        float var = wave_sum64(dv * dv) * (1.0f / 64.0f);
        out[(size_t)(node0 + r) * 64 + lane] =
            dv * (1.0f / sqrtf(var + 1.0e-6f)) * lnsv + lnbv;
    }
}

extern "C" void kernel_launch(void* const* d_in, const int* in_sizes, int n_in,
                              void* d_out, int out_size, void* d_ws, size_t ws_size,
                              hipStream_t stream)
{
    (void)in_sizes; (void)n_in; (void)out_size; (void)ws_size;
    const float* x     = (const float*)d_in[0];
    const float* pos   = (const float*)d_in[1];
    const float* mw    = (const float*)d_in[2];
    const float* osc   = (const float*)d_in[3];
    const float* mplns = (const float*)d_in[4];
    const float* mplnb = (const float*)d_in[5];
    const float* mW1   = (const float*)d_in[6];
    const float* mb1   = (const float*)d_in[7];
    const float* mW2   = (const float*)d_in[8];
    const float* mb2   = (const float*)d_in[9];
    const float* uW1   = (const float*)d_in[10];
    const float* ub1   = (const float*)d_in[11];
    const float* uW2   = (const float*)d_in[12];
    const float* ub2   = (const float*)d_in[13];
    const float* olns  = (const float*)d_in[14];
    const float* olnb  = (const float*)d_in[15];
    float* out = (float*)d_out;

    // ws layout (bytes):
    //   0        nbr    262144
    //   262144   mp     2097152
    //   2359296  ab     4194304
    //   6553600  spk    131072
    //   6684672  boff   36864 (2*4097*4 used)
    //   6721536  mWlt   81920
    //   6803456  mW1tA  16384
    //   6819840  mW1tB  16384
    char* ws = (char*)d_ws;
    int*    nbr   = (int*)ws;
    float*  mp    = (float*)(ws + 262144);
    float*  ab    = (float*)(ws + 2359296);
    float4* spk   = (float4*)(ws + 6553600);
    int*    boff  = (int*)(ws + 6684672);
    float*  mWlt  = (float*)(ws + 6721536);
    float*  mW1tA = (float*)(ws + 6803456);
    float*  mW1tB = (float*)(ws + 6819840);

    prep_kernel<<<8, 1024, 0, stream>>>(pos, spk, boff,
        mw, mW1, mWlt, mW1tA, mW1tB);
    knn_kernel<<<1024, 512, 0, stream>>>(pos, spk, boff, nbr);
    multipole_gemm_kernel<<<256, 512, 0, stream>>>(
        x, pos, mWlt, mW1tA, mW1tB, osc, mplns, mplnb, mp, ab);
    msg_upd_kernel<<<256, 512, 0, stream>>>(
        x, ab, nbr, mp, mb1, mW2, mb2, uW1, ub1, uW2, ub2, olns, olnb, out);
}

// Round 9
// 81.135 us; speedup vs baseline: 2.8894x; 1.0369x over previous
//
#include <hip/hip_runtime.h>
#include <math.h>

// MGNO layer: B=2, N=4096, C=64, ORDER=4, COORD=2, K=8
#define NNODES 4096
#define KNN 8
// 2-D grid: 64x64 cells over [-4.5, 4.5]^2; edge cells absorb clamped points.
#define GX 64
#define NCELL (GX * GX)
#define BOX_LO (-4.5f)
#define CELL_INV (7.11111111f)   // GX / 9.0

__device__ __forceinline__ int binf(float v) {
    int k = (int)floorf((v - BOX_LO) * CELL_INV);
    return min(GX - 1, max(0, k));
}

__device__ __forceinline__ float cleanf(float v) {
    if (v != v) return 0.0f;
    return fminf(fmaxf(v, -1.0e6f), 1.0e6f);
}

__device__ __forceinline__ float gelu_tanh(float v) {
    float v3 = v * v * v;
    float t = tanhf(0.7978845608028654f * (v + 0.044715f * v3));
    return 0.5f * v * (1.0f + t);
}

__device__ __forceinline__ float wave_sum64(float v) {
    #pragma unroll
    for (int off = 32; off > 0; off >>= 1)
        v += __shfl_xor(v, off, 64);
    return v;
}

// ---------------------------------------------------------------------------
// Kernel 0: prep. Blocks 0-1: clean pos, counting-sort into 64x64 cells
// (one block/batch). Blocks 2-7: QUAD-PACK all weight matrices into ws:
// WQ[i/4][j] = float4{W[i..i+3][j]} so GEMM-kernel weight reads become
// lane-CONTIGUOUS b128 (16B lane stride — the canonical fast pattern; R7
// proved the 272-528B strided-column b128 pattern costs ~2x).
// ---------------------------------------------------------------------------
__global__ __launch_bounds__(1024) void prep_kernel(
    const float* __restrict__ pos, float4* __restrict__ spk,
    int* __restrict__ boff,
    const float* __restrict__ mw,  const float* __restrict__ mW1,
    const float* __restrict__ mW2, const float* __restrict__ uW1,
    const float* __restrict__ uW2,
    float4* __restrict__ mWltQ, float4* __restrict__ mW1tAQ,
    float4* __restrict__ mW1tBQ, float4* __restrict__ uW1Q,
    float4* __restrict__ uW2Q, float4* __restrict__ mW2Q)
{
    __shared__ int cnt[NCELL];       // 16 KB; reused as scatter cursor
    __shared__ int wsum[16], wexcl[16];

    if (blockIdx.x >= 2) {
        // ---- weight quad-packs (idle CUs; prep proper is 2 blocks) ----
        int tid = (blockIdx.x - 2) * 1024 + threadIdx.x;  // 0..6143
        const int STEP = 6 * 1024;
        // mWltQ[(o*16+iq)*64+j].k = W[4iq+k][j][o]   (mw flat: (i*64+j)*5+o)
        for (int g = tid; g < 5 * 16 * 64; g += STEP) {
            int o = g >> 10, rem = g & 1023, iq = rem >> 6, j = rem & 63;
            float4 v;
            v.x = mw[((4 * iq + 0) * 64 + j) * 5 + o];
            v.y = mw[((4 * iq + 1) * 64 + j) * 5 + o];
            v.z = mw[((4 * iq + 2) * 64 + j) * 5 + o];
            v.w = mw[((4 * iq + 3) * 64 + j) * 5 + o];
            mWltQ[g] = v;
        }
        // mW1tAQ[iq*64+j].k = mW1[4iq+k][j]; B: rows 64+4iq+k (128x64 halves)
        for (int g = tid; g < 16 * 64; g += STEP) {
            int iq = g >> 6, j = g & 63;
            float4 a, b;
            a.x = mW1[(4 * iq + 0) * 64 + j]; a.y = mW1[(4 * iq + 1) * 64 + j];
            a.z = mW1[(4 * iq + 2) * 64 + j]; a.w = mW1[(4 * iq + 3) * 64 + j];
            b.x = mW1[(64 + 4 * iq + 0) * 64 + j];
            b.y = mW1[(64 + 4 * iq + 1) * 64 + j];
            b.z = mW1[(64 + 4 * iq + 2) * 64 + j];
            b.w = mW1[(64 + 4 * iq + 3) * 64 + j];
            mW1tAQ[g] = a; mW1tBQ[g] = b;
        }
        // uW1Q[iq*128+j].k = uW1[4iq+k][j]   (128x128)
        for (int g = tid; g < 32 * 128; g += STEP) {
            int iq = g >> 7, j = g & 127;
            float4 v;
            v.x = uW1[(4 * iq + 0) * 128 + j]; v.y = uW1[(4 * iq + 1) * 128 + j];
            v.z = uW1[(4 * iq + 2) * 128 + j]; v.w = uW1[(4 * iq + 3) * 128 + j];
            uW1Q[g] = v;
        }
        // uW2Q[hq*64+j].k = uW2[4hq+k][j]   (128x64)
        for (int g = tid; g < 32 * 64; g += STEP) {
            int hq = g >> 6, j = g & 63;
            float4 v;
            v.x = uW2[(4 * hq + 0) * 64 + j]; v.y = uW2[(4 * hq + 1) * 64 + j];
            v.z = uW2[(4 * hq + 2) * 64 + j]; v.w = uW2[(4 * hq + 3) * 64 + j];
            uW2Q[g] = v;
        }
        // mW2Q[hq*64+j].k = mW2[4hq+k][j]   (64x64)
        for (int g = tid; g < 16 * 64; g += STEP) {
            int hq = g >> 6, j = g & 63;
            float4 v;
            v.x = mW2[(4 * hq + 0) * 64 + j]; v.y = mW2[(4 * hq + 1) * 64 + j];
            v.z = mW2[(4 * hq + 2) * 64 + j]; v.w = mW2[(4 * hq + 3) * 64 + j];
            mW2Q[g] = v;
        }
        return;
    }

    int b    = blockIdx.x;
    int t    = threadIdx.x;
    int wid  = t >> 6;
    int lane = t & 63;
    const float2* pb = (const float2*)(pos + (size_t)b * NNODES * 2);

    float qx[4], qy[4];
    int ck[4];
    #pragma unroll
    for (int s = 0; s < 4; ++s) cnt[t + s * 1024] = 0;
    __syncthreads();

    #pragma unroll
    for (int s = 0; s < 4; ++s) {
        float2 p = pb[t + s * 1024];
        qx[s] = cleanf(p.x); qy[s] = cleanf(p.y);
        ck[s] = binf(qy[s]) * GX + binf(qx[s]);
        atomicAdd(&cnt[ck[s]], 1);
    }
    __syncthreads();

    // exclusive prefix scan of cnt[4096]: 4 cells/thread + wave/block scan
    int c0 = cnt[4 * t], c1 = cnt[4 * t + 1], c2 = cnt[4 * t + 2], c3 = cnt[4 * t + 3];
    int s4 = c0 + c1 + c2 + c3;
    int sc = s4;
    #pragma unroll
    for (int off = 1; off < 64; off <<= 1) {
        int o = __shfl_up(sc, off, 64);
        if (lane >= off) sc += o;
    }
    if (lane == 63) wsum[wid] = sc;
    __syncthreads();
    if (t < 16) {
        int v = wsum[t];
        #pragma unroll
        for (int off = 1; off < 16; off <<= 1) {
            int o = __shfl_up(v, off, 64);
            if (t >= off) v += o;
        }
        wexcl[t] = v - wsum[t];
    }
    __syncthreads();
    int base = wexcl[wid] + (sc - s4);
    int* bofb = boff + b * (NCELL + 1);
    bofb[4 * t]     = base;
    bofb[4 * t + 1] = base + c0;
    bofb[4 * t + 2] = base + c0 + c1;
    bofb[4 * t + 3] = base + c0 + c1 + c2;
    if (t == 0) bofb[NCELL] = NNODES;
    cnt[4 * t]     = base;
    cnt[4 * t + 1] = base + c0;
    cnt[4 * t + 2] = base + c0 + c1;
    cnt[4 * t + 3] = base + c0 + c1 + c2;
    __syncthreads();

    #pragma unroll
    for (int s = 0; s < 4; ++s) {
        int p = atomicAdd(&cnt[ck[s]], 1);
        spk[(size_t)b * NNODES + p] =
            make_float4(qx[s], qy[s], __int_as_float(t + s * 1024), 0.0f);
    }
}

#define INSERT8(cur)                                                     \
    {                                                                    \
        unsigned long long c_ = (cur);                                   \
        _Pragma("unroll")                                                \
        for (int q_ = 0; q_ < 8; ++q_) {                                 \
            unsigned long long mn_ = (c_ < best[q_]) ? c_ : best[q_];    \
            c_ = (c_ < best[q_]) ? best[q_] : c_;                        \
            best[q_] = mn_;                                              \
        }                                                                \
    }

// ---------------------------------------------------------------------------
// Kernel 1: exact 8-NN via 2-D cell grid, one wave per query row.
// R2 verbatim + FAST PATH: when the exact window [q +- sqrt(U)] is contained
// in the already-swept A-square, Phase B sweeps nothing and the final merge
// would just re-derive m8 — emit m8 directly (wave-uniform branch; selection
// guarantee unchanged: containment => every candidate with d2 <= U swept).
// ---------------------------------------------------------------------------
__global__ __launch_bounds__(512) void knn_kernel(
    const float* __restrict__ pos, const float4* __restrict__ spk,
    const int* __restrict__ boff, int* __restrict__ nbr)
{
    int wid  = threadIdx.x >> 6;
    int lane = threadIdx.x & 63;
    int row  = blockIdx.x * 8 + wid;          // 0..8191
    int b    = row >> 12;
    int i    = row & 4095;

    const float4* sp = spk + (size_t)b * NNODES;
    const int*    bo = boff + b * (NCELL + 1);

    float2 pr = ((const float2*)(pos + (size_t)b * NNODES * 2))[i];
    float qx = cleanf(pr.x), qy = cleanf(pr.y);
    int qcx = binf(qx), qcy = binf(qy);

    unsigned long long best[8];
    #pragma unroll
    for (int q = 0; q < 8; ++q) best[q] = ~0ull;

    auto sweep = [&](int s0, int s1) {
        for (int p0 = s0; p0 < s1; p0 += 64) {
            int p = p0 + lane;
            bool valid = (p < s1);
            float4 cp = sp[min(p, s1 - 1)];
            int ci = __float_as_int(cp.z);
            float dx = qx - cp.x, dy = qy - cp.y;
            float d2 = __fadd_rn(__fmul_rn(dx, dx), __fmul_rn(dy, dy));
            unsigned long long cur =
                ((unsigned long long)__float_as_uint(d2) << 32) | (unsigned)ci;
            if (!valid || ci == i) cur = ~0ull;
            INSERT8(cur);
        }
    };

    // ---- phase A: widen square (counts only) until >= 9 points ----
    int r = 1, cxL, cxH, cyL, cyH;
    for (;;) {
        cxL = max(qcx - r, 0); cxH = min(qcx + r, GX - 1);
        cyL = max(qcy - r, 0); cyH = min(qcy + r, GX - 1);
        int cnt = 0;
        for (int cy = cyL; cy <= cyH; ++cy)
            cnt += bo[cy * GX + cxH + 1] - bo[cy * GX + cxL];
        if (cnt >= 9 || (cxL == 0 && cxH == GX - 1 && cyL == 0 && cyH == GX - 1))
            break;
        r += (r < 4) ? 1 : (r >> 1);         // geometric growth in tails
    }
    for (int cy = cyL; cy <= cyH; ++cy)
        sweep(bo[cy * GX + cxL], bo[cy * GX + cxH + 1]);

    // ---- extract exact top-8 of phase A (ascending) into m8[] ----
    unsigned long long m8[8];
    #pragma unroll
    for (int rr = 0; rr < 8; ++rr) {
        unsigned long long k = best[0];
        #pragma unroll
        for (int off = 32; off > 0; off >>= 1) {
            unsigned long long o = __shfl_xor(k, off, 64);
            k = (o < k) ? o : k;
        }
        m8[rr] = k;
        if (best[0] == k) {
            #pragma unroll
            for (int q = 0; q < 7; ++q) best[q] = best[q + 1];
            best[7] = ~0ull;
        }
    }

    // window half-width from U = 8th-smallest d2 (finite by construction)
    float U = __uint_as_float((unsigned)(m8[7] >> 32));
    float w = sqrtf(U) * 1.0001f + 1.0e-5f;
    int bxlo = binf(qx - w), bxhi = binf(qx + w);
    int bylo = binf(qy - w), byhi = binf(qy + w);

    // ---- fast path: window inside A-square -> m8 is exact, emit it ----
    if (bxlo >= cxL && bxhi <= cxH && bylo >= cyL && byhi <= cyH) {
        unsigned long long v = m8[0];
        #pragma unroll
        for (int rr = 1; rr < 8; ++rr) v = (lane == rr) ? m8[rr] : v;
        if (lane < 8) nbr[(size_t)row * KNN + lane] = (int)(unsigned)v;
        return;
    }

    // reinit per-lane lists; inject m8[r] into lane r (static-index select)
    #pragma unroll
    for (int q = 0; q < 8; ++q) best[q] = ~0ull;
    unsigned long long inj = m8[0];
    #pragma unroll
    for (int rr = 1; rr < 8; ++rr) inj = (lane == rr) ? m8[rr] : inj;
    if (lane < 8) best[0] = inj;

    // ---- phase B: B-square minus A-square (exact exclusion, no dup keys) ----
    for (int cy = bylo; cy <= byhi; ++cy) {
        int rl = bo[cy * GX + bxlo], rh = bo[cy * GX + bxhi + 1];
        if (cy >= cyL && cy <= cyH) {
            int e = bo[cy * GX + min(cxL, bxhi + 1)];   // left of A-cols
            sweep(rl, e);
            int s = bo[cy * GX + max(cxH + 1, bxlo)];   // right of A-cols
            sweep(s, rh);
        } else {
            sweep(rl, rh);
        }
    }

    // ---- final merge: 8 rounds of butterfly wave-min + pop ----
    unsigned out_j = 0;
    #pragma unroll
    for (int rr = 0; rr < 8; ++rr) {
        unsigned long long k = best[0];
        #pragma unroll
        for (int off = 32; off > 0; off >>= 1) {
            unsigned long long o = __shfl_xor(k, off, 64);
            k = (o < k) ? o : k;
        }
        if (lane == rr) out_j = (unsigned)k;
        if (best[0] == k) {                  // unique keys -> exactly one lane
            #pragma unroll
            for (int q = 0; q < 7; ++q) best[q] = best[q + 1];
            best[7] = ~0ull;
        }
    }
    if (lane < 8) nbr[(size_t)row * KNN + lane] = (int)out_j;
}

// ---------------------------------------------------------------------------
// Kernel 2: fused multipole + msg GEMM. Quad-packed weights: per-iter read
// WQ[iq*64+lane] is lane-contiguous b128 (16B stride — fast pattern), vs the
// R5 per-lane-column 272B-stride reads (R7 measured that pattern ~2x slow).
// Same values, same component order -> bit-exact. Activations broadcast via
// same-address float4 (R2 mechanism). 4 nodes/wave batch.
// LDS: 80K WlQ + 16K WAQ + 16K WBQ + 8.5K xsh + 8.5K xr + csh ~= 130 KB.
// ---------------------------------------------------------------------------
__global__ __launch_bounds__(512) void multipole_gemm_kernel(
    const float* __restrict__ x, const float* __restrict__ pos,
    const float4* __restrict__ mWltQ, const float4* __restrict__ mW1tAQ,
    const float4* __restrict__ mW1tBQ, const float* __restrict__ osc,
    const float* __restrict__ lns, const float* __restrict__ lnb,
    float* __restrict__ mp, float* __restrict__ ab)
{
    __shared__ alignas(16) float4 WlQ[5 * 16 * 64];  // [o][iq][j] 80 KB
    __shared__ alignas(16) float4 WAQ[16 * 64];      // 16 KB
    __shared__ alignas(16) float4 WBQ[16 * 64];      // 16 KB
    __shared__ alignas(16) float xsh[32][68];        // cleaned x, 8.5 KB
    __shared__ alignas(16) float xr[32][68];         // raw x, 8.5 KB
    __shared__ float csh[32][5];                     // per-node c_o
    int base = blockIdx.x * 32;

    // stage quad-packed weights: linear coalesced float4 copies
    for (int g = threadIdx.x; g < 5 * 16 * 64; g += 512) WlQ[g] = mWltQ[g];
    for (int g = threadIdx.x; g < 16 * 64; g += 512) {
        WAQ[g] = mW1tAQ[g];
        WBQ[g] = mW1tBQ[g];
    }
    for (int g = threadIdx.x; g < 32 * 64; g += 512) {
        float v = x[(size_t)base * 64 + g];
        xr[g >> 6][g & 63]  = v;
        xsh[g >> 6][g & 63] = cleanf(v);
    }
    __syncthreads();

    if (threadIdx.x < 32) {
        int t = threadIdx.x;
        float ss = 0.0f;
        for (int i = 0; i < 64; ++i) { float v = xsh[t][i]; ss += v * v; }
        float nx = sqrtf(ss);
        int node = base + t;
        float px = cleanf(pos[(size_t)node * 2]);
        float py = cleanf(pos[(size_t)node * 2 + 1]);
        float r = fmaxf(sqrtf(px * px + py * py), 1.0e-8f);
        float th = atan2f(py, px + 1.0e-8f);
        float r2 = r * r, r3 = r2 * r, r4 = r2 * r2;  // lax.integer_pow order
        float ro[5] = {1.0f, r, r2, r3, r4};
        #pragma unroll
        for (int o = 0; o < 5; ++o) {
            float radial = tanhf(ro[o] / (1.0f + ro[o]));
            float ang = cosf((float)o * th);
            float s = radial * ang;
            float denom = fabsf(s) * nx + 1.0e-8f;     // ||s*x|| + EPS
            float sc = fminf(fmaxf(osc[o], 0.01f), 1.0f);
            csh[t][o] = (s / denom) * sc / (float)(o + 1);
        }
    }
    __syncthreads();

    int w = threadIdx.x >> 6;
    int lane = threadIdx.x & 63;
    int nl0 = w * 4;

    float acc[4][5];
    float accA[4] = {0.f, 0.f, 0.f, 0.f};
    float accB[4] = {0.f, 0.f, 0.f, 0.f};
    #pragma unroll
    for (int r_ = 0; r_ < 4; ++r_)
        #pragma unroll
        for (int o = 0; o < 5; ++o) acc[r_][o] = 0.0f;

    #define MG_FMA(R, XI, XV, QC)                                          \
        { float xi_ = (XI), xv_ = (XV);                                    \
          acc[R][0] += xi_ * q0.QC; acc[R][1] += xi_ * q1.QC;              \
          acc[R][2] += xi_ * q2.QC; acc[R][3] += xi_ * q3.QC;              \
          acc[R][4] += xi_ * q4.QC;                                        \
          accA[R] += xv_ * qa.QC;  accB[R] += xv_ * qb.QC; }

    for (int i4 = 0; i4 < 64; i4 += 4) {   // 7 contig-b128 + 8 bc-b128 / iter
        int iq = i4 >> 2;
        float4 q0 = WlQ[(0 * 16 + iq) * 64 + lane];
        float4 q1 = WlQ[(1 * 16 + iq) * 64 + lane];
        float4 q2 = WlQ[(2 * 16 + iq) * 64 + lane];
        float4 q3 = WlQ[(3 * 16 + iq) * 64 + lane];
        float4 q4 = WlQ[(4 * 16 + iq) * 64 + lane];
        float4 qa = WAQ[iq * 64 + lane];
        float4 qb = WBQ[iq * 64 + lane];
        #pragma unroll
        for (int r_ = 0; r_ < 4; ++r_) {
            float4 xc4 = *(const float4*)&xsh[nl0 + r_][i4];  // broadcast
            float4 xw4 = *(const float4*)&xr[nl0 + r_][i4];   // broadcast
            MG_FMA(r_, xc4.x, xw4.x, x)
            MG_FMA(r_, xc4.y, xw4.y, y)
            MG_FMA(r_, xc4.z, xw4.z, z)
            MG_FMA(r_, xc4.w, xw4.w, w)
        }
    }
    #undef MG_FMA

    float lnsv = lns[lane], lnbv = lnb[lane];
    #pragma unroll
    for (int r_ = 0; r_ < 4; ++r_) {
        int node = base + nl0 + r_;
        float tv = csh[nl0 + r_][0] * acc[r_][0] + csh[nl0 + r_][1] * acc[r_][1]
                 + csh[nl0 + r_][2] * acc[r_][2] + csh[nl0 + r_][3] * acc[r_][3]
                 + csh[nl0 + r_][4] * acc[r_][4];
        float mu = wave_sum64(tv) * (1.0f / 64.0f);
        float dv = tv - mu;
        float var = wave_sum64(dv * dv) * (1.0f / 64.0f);
        float o_ = dv * (1.0f / sqrtf(var + 1.0e-6f)) * lnsv + lnbv;
        if (o_ != o_) o_ = xsh[nl0 + r_][lane];  // where(isnan, cleaned x)
        mp[(size_t)node * 64 + lane] = o_;
        ab[(size_t)node * 128 + lane]      = accA[r_];
        ab[(size_t)node * 128 + 64 + lane] = accB[r_];
    }
}

// ---------------------------------------------------------------------------
// Kernel 3: fused msg-gather + update MLP + final LayerNorm. R8 structure
// (batch-4, no-unroll spill guard, float4 act broadcasts) with quad-packed
// weight reads: 448 b32 -> 112 lane-contiguous b128 per wave. Same values,
// same component order -> bit-exact.
// LDS: 64K W1uQ + 32K W2uQ + 16K W2mQ + 16K ul + 16K hl = 144 KB.
// ---------------------------------------------------------------------------
__global__ __launch_bounds__(512) void msg_upd_kernel(
    const float* __restrict__ x, const float* __restrict__ ab,
    const int* __restrict__ nbr, const float* __restrict__ mp,
    const float* __restrict__ mb1, const float4* __restrict__ mW2Q,
    const float* __restrict__ mb2,
    const float4* __restrict__ uW1Q, const float* __restrict__ ub1,
    const float4* __restrict__ uW2Q, const float* __restrict__ ub2,
    const float* __restrict__ lns, const float* __restrict__ lnb,
    float* __restrict__ out)
{
    __shared__ alignas(16) float4 W1uQ[32 * 128];  // [iq][j] 64 KB
    __shared__ alignas(16) float4 W2uQ[32 * 64];   // [hq][j] 32 KB
    __shared__ alignas(16) float4 W2mQ[16 * 64];   // [hq][j] 16 KB
    __shared__ alignas(16) float ul[8][4][128];    // 16 KB (upd input, 4 nodes)
    __shared__ alignas(16) float hl[8][4][128];    // 16 KB (hm in [0:64], then h)
    int base = blockIdx.x * 32;

    for (int g = threadIdx.x; g < 32 * 128; g += 512) W1uQ[g] = uW1Q[g];
    for (int g = threadIdx.x; g < 32 * 64; g += 512)  W2uQ[g] = uW2Q[g];
    for (int g = threadIdx.x; g < 16 * 64; g += 512)  W2mQ[g] = mW2Q[g];
    __syncthreads();

    int w = threadIdx.x >> 6;
    int lane = threadIdx.x & 63;
    float b1m = mb1[lane], b2m = mb2[lane];
    float b1a = ub1[lane], b1b = ub1[lane + 64], b2u = ub2[lane];
    float lnsv = lns[lane], lnbv = lnb[lane];

    int node0 = base + w * 4;
    const float* abb = ab + (((size_t)(node0 >> 12)) << 12) * 128;  // batch base
    const int* nb = nbr + (size_t)node0 * 8;

    // ---- gather + gelu phase (R2 rolling form; hm -> hl[w][t][0:64]) ----
    float bvc[8];
    {
        int nb0[8];
        #pragma unroll
        for (int k = 0; k < 8; ++k) nb0[k] = nb[k];
        #pragma unroll
        for (int k = 0; k < 8; ++k)
            bvc[k] = abb[(size_t)nb0[k] * 128 + 64 + lane];
    }
    #pragma unroll
    for (int t = 0; t < 4; ++t) {
        int nbn[8];
        if (t < 3) {
            #pragma unroll
            for (int k = 0; k < 8; ++k) nbn[k] = nb[8 * (t + 1) + k];
        }
        float a = ab[(size_t)(node0 + t) * 128 + lane];
        float bvn[8];
        if (t < 3) {
            #pragma unroll
            for (int k = 0; k < 8; ++k)
                bvn[k] = abb[(size_t)nbn[k] * 128 + 64 + lane];
        }
        float hsum = 0.0f;
        #pragma unroll
        for (int k = 0; k < 8; ++k)
            hsum += gelu_tanh(a + bvc[k] + b1m);
        hl[w][t][lane] = hsum * 0.125f;   // same-wave LDS, in-order
        #pragma unroll
        for (int k = 0; k < 8; ++k) bvc[k] = bvn[k];
    }

    // ---- msg W2 batched: lm_r = hm_r @ W2m + b2 (h ascending, same tree) ----
    float o_[4] = {0.f, 0.f, 0.f, 0.f};
    for (int h4 = 0; h4 < 64; h4 += 4) {          // no unroll (spill guard)
        float4 wq = W2mQ[(h4 >> 2) * 64 + lane];  // contig b128: rows h4..h4+3
        #pragma unroll
        for (int r = 0; r < 4; ++r) {
            float4 hv = *(const float4*)&hl[w][r][h4];       // broadcast
            o_[r] += hv.x * wq.x + hv.y * wq.y + hv.z * wq.z + hv.w * wq.w;
        }
    }

    // ---- u = [mp | lm] ----
    #pragma unroll
    for (int r = 0; r < 4; ++r) {
        ul[w][r][lane]      = mp[(size_t)(node0 + r) * 64 + lane];
        ul[w][r][64 + lane] = o_[r] + b2m;
    }

    // ---- upd W1 batched (i ascending 0..127, same tree) ----
    float h1a[4] = {0.f, 0.f, 0.f, 0.f}, h2a[4] = {0.f, 0.f, 0.f, 0.f};
    for (int i4 = 0; i4 < 128; i4 += 4) {         // no unroll (spill guard)
        float4 wA = W1uQ[(i4 >> 2) * 128 + lane];        // rows i4..i4+3, col lane
        float4 wC = W1uQ[(i4 >> 2) * 128 + lane + 64];   // col lane+64
        #pragma unroll
        for (int r = 0; r < 4; ++r) {
            float4 uv = *(const float4*)&ul[w][r][i4];       // broadcast
            h1a[r] += uv.x * wA.x + uv.y * wA.y + uv.z * wA.z + uv.w * wA.w;
            h2a[r] += uv.x * wC.x + uv.y * wC.y + uv.z * wC.z + uv.w * wC.w;
        }
    }
    #pragma unroll
    for (int r = 0; r < 4; ++r) {
        hl[w][r][lane]      = gelu_tanh(h1a[r] + b1a);   // hm now dead
        hl[w][r][64 + lane] = gelu_tanh(h2a[r] + b1b);
    }

    // ---- upd W2 batched (h ascending 0..127, same tree) ----
    float accq[4] = {0.f, 0.f, 0.f, 0.f};
    for (int h4 = 0; h4 < 128; h4 += 4) {         // no unroll (spill guard)
        float4 wq = W2uQ[(h4 >> 2) * 64 + lane];  // rows h4..h4+3, col lane
        #pragma unroll
        for (int r = 0; r < 4; ++r) {
            float4 hv = *(const float4*)&hl[w][r][h4];       // broadcast
            accq[r] += hv.x * wq.x + hv.y * wq.y + hv.z * wq.z + hv.w * wq.w;
        }
    }

    // ---- residual + LayerNorm (identical butterfly) ----
    #pragma unroll
    for (int r = 0; r < 4; ++r) {
        float pre = x[(size_t)(node0 + r) * 64 + lane] + accq[r] + b2u;
        float mu = wave_sum64(pre) * (1.0f / 64.0f);
        float dv = pre - mu;
        float var = wave_sum64(dv * dv) * (1.0f / 64.0f);
        out[(size_t)(node0 + r) * 64 + lane] =
            dv * (1.0f / sqrtf(var + 1.0e-6f)) * lnsv + lnbv;
    }
}

extern "C" void kernel_launch(void* const* d_in, const int* in_sizes, int n_in,
                              void* d_out, int out_size, void* d_ws, size_t ws_size,
                              hipStream_t stream)
{
    (void)in_sizes; (void)n_in; (void)out_size; (void)ws_size;
    const float* x     = (const float*)d_in[0];
    const float* pos   = (const float*)d_in[1];
    const float* mw    = (const float*)d_in[2];
    const float* osc   = (const float*)d_in[3];
    const float* mplns = (const float*)d_in[4];
    const float* mplnb = (const float*)d_in[5];
    const float* mW1   = (const float*)d_in[6];
    const float* mb1   = (const float*)d_in[7];
    const float* mW2   = (const float*)d_in[8];
    const float* mb2   = (const float*)d_in[9];
    const float* uW1   = (const float*)d_in[10];
    const float* ub1   = (const float*)d_in[11];
    const float* uW2   = (const float*)d_in[12];
    const float* ub2   = (const float*)d_in[13];
    const float* olns  = (const float*)d_in[14];
    const float* olnb  = (const float*)d_in[15];
    float* out = (float*)d_out;

    // ws layout (bytes):
    //   0        nbr     262144
    //   262144   mp      2097152
    //   2359296  ab      4194304
    //   6553600  spk     131072
    //   6684672  boff    36864 (2*4097*4 used)
    //   6721536  mWltQ   81920
    //   6803456  mW1tAQ  16384
    //   6819840  mW1tBQ  16384
    //   6836224  uW1Q    65536
    //   6901760  uW2Q    32768
    //   6934528  mW2Q    16384
    char* ws = (char*)d_ws;
    int*    nbr    = (int*)ws;
    float*  mp     = (float*)(ws + 262144);
    float*  ab     = (float*)(ws + 2359296);
    float4* spk    = (float4*)(ws + 6553600);
    int*    boff   = (int*)(ws + 6684672);
    float4* mWltQ  = (float4*)(ws + 6721536);
    float4* mW1tAQ = (float4*)(ws + 6803456);
    float4* mW1tBQ = (float4*)(ws + 6819840);
    float4* uW1Q   = (float4*)(ws + 6836224);
    float4* uW2Q   = (float4*)(ws + 6901760);
    float4* mW2Q   = (float4*)(ws + 6934528);

    prep_kernel<<<8, 1024, 0, stream>>>(pos, spk, boff,
        mw, mW1, mW2, uW1, uW2, mWltQ, mW1tAQ, mW1tBQ, uW1Q, uW2Q, mW2Q);
    knn_kernel<<<1024, 512, 0, stream>>>(pos, spk, boff, nbr);
    multipole_gemm_kernel<<<256, 512, 0, stream>>>(
        x, pos, mWltQ, mW1tAQ, mW1tBQ, osc, mplns, mplnb, mp, ab);
    msg_upd_kernel<<<256, 512, 0, stream>>>(
        x, ab, nbr, mp, mb1, mW2Q, mb2, uW1Q, ub1, uW2Q, ub2, olns, olnb, out);
}